// Round 2
// baseline (239.097 us; speedup 1.0000x reference)
//
#include <hip/hip_runtime.h>
#include <math.h>

#define B_SZ   8
#define S_INN  4096
#define S_OUTT 1024
#define DD     128
#define EPS_LN 1e-5f

typedef _Float16 h8 __attribute__((ext_vector_type(8)));
typedef float f32x4 __attribute__((ext_vector_type(4)));

// ws layout (float offsets):
//   xn    [0,        4194304)   f32  (B,S,D)        dead after kB -> reused by part
//   Nk16  [4194304,  6291456)   f16  (B,S,D)
//   NT    [6291456,  8388608)   f16  (B,D,S)   = Nk16 transposed
//   LT    [8388608, 10485760)   f16  (T,S)     = Linker transposed
#define XN_OFF   0
#define NK16_OFF 4194304
#define NT_OFF   6291456
#define LT_OFF   8388608

// ---------------------------------------------------------------------------
// Kernel A: xn = LayerNorm(x @ M^T) * gamma + beta        (f32, VALU)
// 256 blocks x 256 thr; 128 rows/block; thread=(ig in [0,8), rg in [0,32)),
// 4 rows x 16 cols each. M staged in LDS interleave-swizzled so the 8 ig
// b128 reads per (j,q) hit 8 distinct 4-bank groups (broadcast within group).
// ---------------------------------------------------------------------------
__global__ __launch_bounds__(256) void kA(const float* __restrict__ x,
                                          const float* __restrict__ M,
                                          const float* __restrict__ gamma,
                                          const float* __restrict__ beta,
                                          float* __restrict__ xn) {
    __shared__ float Ms[128 * 128];

    const int tid = threadIdx.x;
    #pragma unroll
    for (int k = 0; k < 16; ++k) {
        int e4 = tid + k * 256;
        int i  = e4 >> 5;
        int j4 = e4 & 31;
        float4 v = *(const float4*)&M[i * DD + j4 * 4];
        int igp = (i >> 4) & 7;
        int qp  = (i >> 2) & 3;
        int cp  = i & 3;
        int col = (qp * 8 + igp) * 4 + cp;
        Ms[(j4 * 4 + 0) * 128 + col] = v.x;
        Ms[(j4 * 4 + 1) * 128 + col] = v.y;
        Ms[(j4 * 4 + 2) * 128 + col] = v.z;
        Ms[(j4 * 4 + 3) * 128 + col] = v.w;
    }
    __syncthreads();

    const int ig = tid & 7;
    const int rg = tid >> 3;
    const int row0 = blockIdx.x * 128 + rg * 4;

    float acc[4][16];
    #pragma unroll
    for (int rr = 0; rr < 4; ++rr)
        #pragma unroll
        for (int k = 0; k < 16; ++k) acc[rr][k] = 0.f;

    const float4* xr[4];
    #pragma unroll
    for (int rr = 0; rr < 4; ++rr) xr[rr] = (const float4*)&x[(size_t)(row0 + rr) * DD];

    for (int j4 = 0; j4 < 32; ++j4) {
        float xvf[4][4];
        #pragma unroll
        for (int rr = 0; rr < 4; ++rr) {
            float4 t = xr[rr][j4];
            xvf[rr][0] = t.x; xvf[rr][1] = t.y; xvf[rr][2] = t.z; xvf[rr][3] = t.w;
        }
        #pragma unroll
        for (int c = 0; c < 4; ++c) {
            const float* Mrow = &Ms[(j4 * 4 + c) * 128];
            #pragma unroll
            for (int q = 0; q < 4; ++q) {
                const float4 mv = *(const float4*)&Mrow[(q * 8 + ig) * 4];
                #pragma unroll
                for (int rr = 0; rr < 4; ++rr) {
                    acc[rr][q * 4 + 0] = fmaf(xvf[rr][c], mv.x, acc[rr][q * 4 + 0]);
                    acc[rr][q * 4 + 1] = fmaf(xvf[rr][c], mv.y, acc[rr][q * 4 + 1]);
                    acc[rr][q * 4 + 2] = fmaf(xvf[rr][c], mv.z, acc[rr][q * 4 + 2]);
                    acc[rr][q * 4 + 3] = fmaf(xvf[rr][c], mv.w, acc[rr][q * 4 + 3]);
                }
            }
        }
    }

    float g[16], be[16];
    #pragma unroll
    for (int q = 0; q < 4; ++q) {
        float4 gv = *(const float4*)&gamma[ig * 16 + q * 4];
        float4 bv = *(const float4*)&beta[ig * 16 + q * 4];
        g[q*4+0]=gv.x; g[q*4+1]=gv.y; g[q*4+2]=gv.z; g[q*4+3]=gv.w;
        be[q*4+0]=bv.x; be[q*4+1]=bv.y; be[q*4+2]=bv.z; be[q*4+3]=bv.w;
    }
    #pragma unroll
    for (int rr = 0; rr < 4; ++rr) {
        float s1 = 0.f, s2 = 0.f;
        #pragma unroll
        for (int k = 0; k < 16; ++k) { s1 += acc[rr][k]; s2 = fmaf(acc[rr][k], acc[rr][k], s2); }
        #pragma unroll
        for (int m = 1; m < 8; m <<= 1) {
            s1 += __shfl_xor(s1, m, 64);
            s2 += __shfl_xor(s2, m, 64);
        }
        float mu  = s1 * (1.f / 128.f);
        float var = s2 * (1.f / 128.f) - mu * mu;
        float rstd = rsqrtf(var + EPS_LN);
        float* dst = &xn[(size_t)(row0 + rr) * DD + ig * 16];
        #pragma unroll
        for (int q = 0; q < 4; ++q) {
            float4 o;
            o.x = (acc[rr][q*4+0] - mu) * rstd * g[q*4+0] + be[q*4+0];
            o.y = (acc[rr][q*4+1] - mu) * rstd * g[q*4+1] + be[q*4+1];
            o.z = (acc[rr][q*4+2] - mu) * rstd * g[q*4+2] + be[q*4+2];
            o.w = (acc[rr][q*4+3] - mu) * rstd * g[q*4+3] + be[q*4+3];
            *(float4*)&dst[q * 4] = o;
        }
    }
}

// ---------------------------------------------------------------------------
// Kernel B: Nk16[b,s,i] = (f16) sum_j xn[b,s,j] * P[i,j] * cos(2*pi*s/(i*128+j+2))
// grid 4096 (one per s) x 256 thr; thread=(i=tid>>1, jh=tid&1), 64 j each,
// 8 batch accumulators amortize each phi 8x. phi via exact int-mod + v_cos
// (revolutions input). P staged pad-132 rows.
// ---------------------------------------------------------------------------
__global__ __launch_bounds__(256) void kB(const float* __restrict__ xn,
                                          const float* __restrict__ P,
                                          _Float16* __restrict__ nk16) {
    const int s = blockIdx.x;
    __shared__ float xs[B_SZ * DD];
    __shared__ float Ps[128 * 132];

    const int tid = threadIdx.x;
    {
        int b = tid >> 5, c4 = tid & 31;
        *(float4*)&xs[b * DD + c4 * 4] =
            *(const float4*)&xn[((size_t)b * S_INN + s) * DD + c4 * 4];
    }
    #pragma unroll
    for (int k = 0; k < 16; ++k) {
        int e4 = tid + k * 256;
        int ip = e4 >> 5, j4 = e4 & 31;
        *(float4*)&Ps[ip * 132 + j4 * 4] = *(const float4*)&P[ip * DD + j4 * 4];
    }
    __syncthreads();

    const int i  = tid >> 1;
    const int jh = tid & 1;
    const float kf = (float)s;
    const float* prow = &Ps[i * 132 + jh * 64];
    const float* xrow = &xs[jh * 64];

    float acc[8] = {0.f,0.f,0.f,0.f,0.f,0.f,0.f,0.f};

    #pragma unroll 2
    for (int j4 = 0; j4 < 16; ++j4) {
        float4 pv = *(const float4*)&prow[j4 * 4];
        float pvf[4] = {pv.x, pv.y, pv.z, pv.w};
        float w[4];
        #pragma unroll
        for (int c = 0; c < 4; ++c) {
            int jj = jh * 64 + j4 * 4 + c;
            float pf = (float)(i * DD + jj + 2);
            float invp = __builtin_amdgcn_rcpf(pf);
            float q  = floorf(kf * invp);
            float rem = fmaf(-q, pf, kf);        // exact (ints < 2^24)
            float r  = rem * invp;
            r = r - floorf(r);                   // [0,1) revolutions
            float ph = __builtin_amdgcn_cosf(r); // cos(2*pi*r)
            w[c] = pvf[c] * ph;
        }
        #pragma unroll
        for (int b = 0; b < 8; ++b) {
            float4 xv = *(const float4*)&xrow[b * DD + j4 * 4];
            acc[b] = fmaf(w[0], xv.x, acc[b]);
            acc[b] = fmaf(w[1], xv.y, acc[b]);
            acc[b] = fmaf(w[2], xv.z, acc[b]);
            acc[b] = fmaf(w[3], xv.w, acc[b]);
        }
    }

    #pragma unroll
    for (int b = 0; b < 8; ++b) acc[b] += __shfl_xor(acc[b], 1, 64);
    if (jh == 0) {
        #pragma unroll
        for (int b = 0; b < 8; ++b)
            nk16[((size_t)b * S_INN + s) * DD + i] = (_Float16)acc[b];
    }
}

// ---------------------------------------------------------------------------
// kXf: transpose+convert f32 (R x C) -> f16 (C x R), 64x64 LDS tiles.
// grid (R/64, C/64, batches). Used for Linker (4096 x 1024) -> LT.
// ---------------------------------------------------------------------------
__global__ __launch_bounds__(256) void kXf(const float* __restrict__ src,
                                           _Float16* __restrict__ dst,
                                           int R, int C) {
    const size_t sb = (size_t)blockIdx.z * (size_t)R * C;
    const int r0 = blockIdx.x * 64, c0 = blockIdx.y * 64;
    __shared__ float tile[64][68];
    const int tid = threadIdx.x;
    {
        const int lr = tid >> 2, lc = (tid & 3) * 16;
        const float4* srow = (const float4*)&src[sb + (size_t)(r0 + lr) * C + c0 + lc];
        float4 v0 = srow[0], v1 = srow[1], v2 = srow[2], v3 = srow[3];
        *(float4*)&tile[lr][lc +  0] = v0;
        *(float4*)&tile[lr][lc +  4] = v1;
        *(float4*)&tile[lr][lc +  8] = v2;
        *(float4*)&tile[lr][lc + 12] = v3;
    }
    __syncthreads();
    {
        const int wc = tid >> 2, wsx = (tid & 3) * 16;
        h8 o0, o1;
        #pragma unroll
        for (int k = 0; k < 8; ++k) o0[k] = (_Float16)tile[wsx + k][wc];
        #pragma unroll
        for (int k = 0; k < 8; ++k) o1[k] = (_Float16)tile[wsx + 8 + k][wc];
        _Float16* drow = &dst[sb + (size_t)(c0 + wc) * R + r0 + wsx];
        *(h8*)&drow[0] = o0;
        *(h8*)&drow[8] = o1;
    }
}

// ---------------------------------------------------------------------------
// kXh: transpose f16 (R x C) -> f16 (C x R), 64x64 LDS tiles.
// grid (R/64, C/64, batches). Used for Nk16 (per b: 4096 x 128) -> NT.
// ---------------------------------------------------------------------------
__global__ __launch_bounds__(256) void kXh(const _Float16* __restrict__ src,
                                           _Float16* __restrict__ dst,
                                           int R, int C) {
    const size_t sb = (size_t)blockIdx.z * (size_t)R * C;
    const int r0 = blockIdx.x * 64, c0 = blockIdx.y * 64;
    __shared__ _Float16 tile[64][72];
    const int tid = threadIdx.x;
    {
        const int lr = tid >> 2, lc = (tid & 3) * 16;
        const h8* srow = (const h8*)&src[sb + (size_t)(r0 + lr) * C + c0 + lc];
        h8 v0 = srow[0], v1 = srow[1];
        *(h8*)&tile[lr][lc + 0] = v0;
        *(h8*)&tile[lr][lc + 8] = v1;
    }
    __syncthreads();
    {
        const int wc = tid >> 2, wsx = (tid & 3) * 16;
        h8 o0, o1;
        #pragma unroll
        for (int k = 0; k < 8; ++k) o0[k] = tile[wsx + k][wc];
        #pragma unroll
        for (int k = 0; k < 8; ++k) o1[k] = tile[wsx + 8 + k][wc];
        _Float16* drow = &dst[sb + (size_t)(c0 + wc) * R + r0 + wsx];
        *(h8*)&drow[0] = o0;
        *(h8*)&drow[8] = o1;
    }
}

// ---------------------------------------------------------------------------
// Kernel C (MFMA): part[kz,b,t,i] = sum_{s in 1024-chunk kz} Nk[b,s,i]*L[s,t]
// grid (16 t-tiles, 8 b, 4 kz) x 256 thr (4 waves). Wave: 16t x 128i tile,
// 32 K-steps of 32. A-frag from LT[t][s], B-frag from NT[b*128+i][s] — both
// k-contiguous 16B direct global loads (L3-resident). mfma_f32_16x16x32_f16,
// f32 accumulate. C mapping: col=lane&15 (i-in-tile), row=(lane>>4)*4+reg (t).
// ---------------------------------------------------------------------------
__global__ __launch_bounds__(256) void kC(const _Float16* __restrict__ NT,
                                          const _Float16* __restrict__ LT,
                                          float* __restrict__ part) {
    const int b = blockIdx.y, kz = blockIdx.z;
    const int wave = threadIdx.x >> 6, lane = threadIdx.x & 63;
    const int t0 = blockIdx.x * 64 + wave * 16;
    const int s_base = kz * 1024;
    const int lr = lane & 15, lh = lane >> 4;

    const _Float16* Arow = &LT[(size_t)(t0 + lr) * S_INN + s_base + lh * 8];
    const _Float16* B0   = &NT[((size_t)b * DD + lr) * S_INN + s_base + lh * 8];

    f32x4 acc[8];
    #pragma unroll
    for (int n = 0; n < 8; ++n) acc[n] = (f32x4){0.f, 0.f, 0.f, 0.f};

    #pragma unroll 2
    for (int ks = 0; ks < 32; ++ks) {
        h8 a = *(const h8*)(Arow + ks * 32);
        #pragma unroll
        for (int n = 0; n < 8; ++n) {
            h8 bb = *(const h8*)(B0 + (size_t)n * 16 * S_INN + ks * 32);
            acc[n] = __builtin_amdgcn_mfma_f32_16x16x32_f16(a, bb, acc[n], 0, 0, 0);
        }
    }

    float* dst = &part[((size_t)kz * B_SZ + b) * S_OUTT * DD];
    #pragma unroll
    for (int n = 0; n < 8; ++n)
        #pragma unroll
        for (int r = 0; r < 4; ++r)
            dst[(size_t)(t0 + lh * 4 + r) * DD + n * 16 + lr] = acc[n][r];
}

// ---------------------------------------------------------------------------
// Kernel D: out = sum of the 4 K-split partials
// ---------------------------------------------------------------------------
__global__ __launch_bounds__(256) void kD(const float* __restrict__ part,
                                          float* __restrict__ out) {
    const int e4 = blockIdx.x * 256 + threadIdx.x;
    const float4* p = (const float4*)part;
    float4 a  = p[e4];
    float4 b1 = p[e4 + 262144];
    float4 c1 = p[e4 + 2 * 262144];
    float4 d1 = p[e4 + 3 * 262144];
    float4 o;
    o.x = a.x + b1.x + c1.x + d1.x;
    o.y = a.y + b1.y + c1.y + d1.y;
    o.z = a.z + b1.z + c1.z + d1.z;
    o.w = a.w + b1.w + c1.w + d1.w;
    ((float4*)out)[e4] = o;
}

extern "C" void kernel_launch(void* const* d_in, const int* in_sizes, int n_in,
                              void* d_out, int out_size, void* d_ws, size_t ws_size,
                              hipStream_t stream) {
    const float* x     = (const float*)d_in[0];
    const float* M     = (const float*)d_in[1];
    const float* P     = (const float*)d_in[2];
    const float* Lk    = (const float*)d_in[3];
    const float* gamma = (const float*)d_in[4];
    const float* beta  = (const float*)d_in[5];
    float* out = (float*)d_out;

    float* wsf = (float*)d_ws;
    float*     xn   = wsf + XN_OFF;                 // f32 (B,S,D)
    _Float16*  nk16 = (_Float16*)(wsf + NK16_OFF);  // f16 (B,S,D)
    _Float16*  NT   = (_Float16*)(wsf + NT_OFF);    // f16 (B,D,S)
    _Float16*  LT   = (_Float16*)(wsf + LT_OFF);    // f16 (T,S)
    float*     part = wsf + XN_OFF;                 // reuse xn region

    hipLaunchKernelGGL(kA,  dim3(256),        dim3(256), 0, stream, x, M, gamma, beta, xn);
    hipLaunchKernelGGL(kB,  dim3(4096),       dim3(256), 0, stream, xn, P, nk16);
    hipLaunchKernelGGL(kXh, dim3(64, 2, 8),   dim3(256), 0, stream, nk16, NT, S_INN, DD);
    hipLaunchKernelGGL(kXf, dim3(64, 16, 1),  dim3(256), 0, stream, Lk, LT, S_INN, S_OUTT);
    hipLaunchKernelGGL(kC,  dim3(16, 8, 4),   dim3(256), 0, stream, NT, LT, part);
    hipLaunchKernelGGL(kD,  dim3(1024),       dim3(256), 0, stream, part, out);
}

// Round 5
// 184.185 us; speedup vs baseline: 1.2981x; 1.2981x over previous
//
#include <hip/hip_runtime.h>
#include <math.h>

#define B_SZ   8
#define S_INN  4096
#define S_OUTT 1024
#define DD     128
#define EPS_LN 1e-5f

typedef _Float16 h8 __attribute__((ext_vector_type(8)));
typedef float f32x4 __attribute__((ext_vector_type(4)));

// ws layout (float offsets):
//   xn    [0,        4194304)   f32  (B,S,D)        dead after kB -> reused by part
//   Nk16  [4194304,  6291456)   f16  (B,S,D)
//   NT    [6291456,  8388608)   f16  (B,D,S)   = Nk16 transposed  (= B-matrix [b*128+i][s])
//   LT    [8388608, 10485760)   f16  (T,S)     = Linker transposed
#define XN_OFF   0
#define NK16_OFF 4194304
#define NT_OFF   6291456
#define LT_OFF   8388608

__device__ __forceinline__ void gload16(const void* g, void* l) {
    __builtin_amdgcn_global_load_lds(
        (const __attribute__((address_space(1))) unsigned int*)g,
        (__attribute__((address_space(3))) unsigned int*)l, 16, 0, 0);
}

// ---------------------------------------------------------------------------
// Kernel A: xn = LayerNorm(x @ M^T) * gamma + beta        (f32, VALU)
// ---------------------------------------------------------------------------
__global__ __launch_bounds__(256) void kA(const float* __restrict__ x,
                                          const float* __restrict__ M,
                                          const float* __restrict__ gamma,
                                          const float* __restrict__ beta,
                                          float* __restrict__ xn) {
    __shared__ float Ms[128 * 128];

    const int tid = threadIdx.x;
    #pragma unroll
    for (int k = 0; k < 16; ++k) {
        int e4 = tid + k * 256;
        int i  = e4 >> 5;
        int j4 = e4 & 31;
        float4 v = *(const float4*)&M[i * DD + j4 * 4];
        int igp = (i >> 4) & 7;
        int qp  = (i >> 2) & 3;
        int cp  = i & 3;
        int col = (qp * 8 + igp) * 4 + cp;
        Ms[(j4 * 4 + 0) * 128 + col] = v.x;
        Ms[(j4 * 4 + 1) * 128 + col] = v.y;
        Ms[(j4 * 4 + 2) * 128 + col] = v.z;
        Ms[(j4 * 4 + 3) * 128 + col] = v.w;
    }
    __syncthreads();

    const int ig = tid & 7;
    const int rg = tid >> 3;
    const int row0 = blockIdx.x * 128 + rg * 4;

    float acc[4][16];
    #pragma unroll
    for (int rr = 0; rr < 4; ++rr)
        #pragma unroll
        for (int k = 0; k < 16; ++k) acc[rr][k] = 0.f;

    const float4* xr[4];
    #pragma unroll
    for (int rr = 0; rr < 4; ++rr) xr[rr] = (const float4*)&x[(size_t)(row0 + rr) * DD];

    for (int j4 = 0; j4 < 32; ++j4) {
        float xvf[4][4];
        #pragma unroll
        for (int rr = 0; rr < 4; ++rr) {
            float4 t = xr[rr][j4];
            xvf[rr][0] = t.x; xvf[rr][1] = t.y; xvf[rr][2] = t.z; xvf[rr][3] = t.w;
        }
        #pragma unroll
        for (int c = 0; c < 4; ++c) {
            const float* Mrow = &Ms[(j4 * 4 + c) * 128];
            #pragma unroll
            for (int q = 0; q < 4; ++q) {
                const float4 mv = *(const float4*)&Mrow[(q * 8 + ig) * 4];
                #pragma unroll
                for (int rr = 0; rr < 4; ++rr) {
                    acc[rr][q * 4 + 0] = fmaf(xvf[rr][c], mv.x, acc[rr][q * 4 + 0]);
                    acc[rr][q * 4 + 1] = fmaf(xvf[rr][c], mv.y, acc[rr][q * 4 + 1]);
                    acc[rr][q * 4 + 2] = fmaf(xvf[rr][c], mv.z, acc[rr][q * 4 + 2]);
                    acc[rr][q * 4 + 3] = fmaf(xvf[rr][c], mv.w, acc[rr][q * 4 + 3]);
                }
            }
        }
    }

    float g[16], be[16];
    #pragma unroll
    for (int q = 0; q < 4; ++q) {
        float4 gv = *(const float4*)&gamma[ig * 16 + q * 4];
        float4 bv = *(const float4*)&beta[ig * 16 + q * 4];
        g[q*4+0]=gv.x; g[q*4+1]=gv.y; g[q*4+2]=gv.z; g[q*4+3]=gv.w;
        be[q*4+0]=bv.x; be[q*4+1]=bv.y; be[q*4+2]=bv.z; be[q*4+3]=bv.w;
    }
    #pragma unroll
    for (int rr = 0; rr < 4; ++rr) {
        float s1 = 0.f, s2 = 0.f;
        #pragma unroll
        for (int k = 0; k < 16; ++k) { s1 += acc[rr][k]; s2 = fmaf(acc[rr][k], acc[rr][k], s2); }
        #pragma unroll
        for (int m = 1; m < 8; m <<= 1) {
            s1 += __shfl_xor(s1, m, 64);
            s2 += __shfl_xor(s2, m, 64);
        }
        float mu  = s1 * (1.f / 128.f);
        float var = s2 * (1.f / 128.f) - mu * mu;
        float rstd = rsqrtf(var + EPS_LN);
        float* dst = &xn[(size_t)(row0 + rr) * DD + ig * 16];
        #pragma unroll
        for (int q = 0; q < 4; ++q) {
            float4 o;
            o.x = (acc[rr][q*4+0] - mu) * rstd * g[q*4+0] + be[q*4+0];
            o.y = (acc[rr][q*4+1] - mu) * rstd * g[q*4+1] + be[q*4+1];
            o.z = (acc[rr][q*4+2] - mu) * rstd * g[q*4+2] + be[q*4+2];
            o.w = (acc[rr][q*4+3] - mu) * rstd * g[q*4+3] + be[q*4+3];
            *(float4*)&dst[q * 4] = o;
        }
    }
}

// ---------------------------------------------------------------------------
// Kernel B: Nk16[b,s,i] = (f16) sum_j xn[b,s,j] * P[i,j] * cos(2*pi*s/(i*128+j+2))
// grid 4096 (one per s) x 256 thr; thread = (il=tid>>2 in [0,64), jq=tid&3):
// owns i in {il, il+64}, j in [jq*32, jq*32+32). 2 P-reads + 8 x-reads per
// 64 FMAs (1.8x less LDS traffic than 1-i layout); phi count unchanged.
// xs rows chunk-permuted (slot=(c&24)|((c+(c>>3))&7)) so the 4 jq-groups'
// 128B-strided chunks land on distinct bank quads. 4-lane shfl_xor reduce.
// ---------------------------------------------------------------------------
__global__ __launch_bounds__(256) void kB(const float* __restrict__ xn,
                                          const float* __restrict__ P,
                                          _Float16* __restrict__ nk16) {
    const int s = blockIdx.x;
    __shared__ float xs[B_SZ * DD];
    __shared__ float Ps[128 * 132];

    const int tid = threadIdx.x;
    {
        int b = tid >> 5, c4 = tid & 31;
        int slot = (c4 & 24) | ((c4 + (c4 >> 3)) & 7);
        *(float4*)&xs[b * DD + slot * 4] =
            *(const float4*)&xn[((size_t)b * S_INN + s) * DD + c4 * 4];
    }
    #pragma unroll
    for (int k = 0; k < 16; ++k) {
        int e4 = tid + k * 256;
        int ip = e4 >> 5, j4 = e4 & 31;
        *(float4*)&Ps[ip * 132 + j4 * 4] = *(const float4*)&P[ip * DD + j4 * 4];
    }
    __syncthreads();

    const int il = tid >> 2;          // [0,64): i-pair {il, il+64}
    const int jq = tid & 3;           // [0,4):  j in [jq*32, jq*32+32)
    const float kf = (float)s;
    const float* prow0 = &Ps[il * 132 + jq * 32];
    const float* prow1 = &Ps[(il + 64) * 132 + jq * 32];

    float acc0[8] = {0.f,0.f,0.f,0.f,0.f,0.f,0.f,0.f};
    float acc1[8] = {0.f,0.f,0.f,0.f,0.f,0.f,0.f,0.f};

    #pragma unroll 2
    for (int j4 = 0; j4 < 8; ++j4) {
        float4 pv0 = *(const float4*)&prow0[j4 * 4];
        float4 pv1 = *(const float4*)&prow1[j4 * 4];
        float p0f[4] = {pv0.x, pv0.y, pv0.z, pv0.w};
        float p1f[4] = {pv1.x, pv1.y, pv1.z, pv1.w};
        float w0[4], w1[4];
        #pragma unroll
        for (int c = 0; c < 4; ++c) {
            int jj = jq * 32 + j4 * 4 + c;
            // i = il
            float pf0 = (float)(il * DD + jj + 2);
            float iv0 = __builtin_amdgcn_rcpf(pf0);
            float q0  = floorf(kf * iv0);
            float rm0 = fmaf(-q0, pf0, kf);        // exact (ints < 2^24)
            float r0  = rm0 * iv0;
            r0 = r0 - floorf(r0);                  // [0,1) revolutions
            w0[c] = p0f[c] * __builtin_amdgcn_cosf(r0);
            // i = il + 64
            float pf1 = pf0 + 8192.f;
            float iv1 = __builtin_amdgcn_rcpf(pf1);
            float q1  = floorf(kf * iv1);
            float rm1 = fmaf(-q1, pf1, kf);
            float r1  = rm1 * iv1;
            r1 = r1 - floorf(r1);
            w1[c] = p1f[c] * __builtin_amdgcn_cosf(r1);
        }
        const int slot = ((jq * 8) | ((j4 + jq) & 7)) * 4;   // permuted chunk
        #pragma unroll
        for (int b = 0; b < 8; ++b) {
            float4 xv = *(const float4*)&xs[b * DD + slot];
            acc0[b] = fmaf(w0[0], xv.x, acc0[b]);
            acc0[b] = fmaf(w0[1], xv.y, acc0[b]);
            acc0[b] = fmaf(w0[2], xv.z, acc0[b]);
            acc0[b] = fmaf(w0[3], xv.w, acc0[b]);
            acc1[b] = fmaf(w1[0], xv.x, acc1[b]);
            acc1[b] = fmaf(w1[1], xv.y, acc1[b]);
            acc1[b] = fmaf(w1[2], xv.z, acc1[b]);
            acc1[b] = fmaf(w1[3], xv.w, acc1[b]);
        }
    }

    #pragma unroll
    for (int m = 1; m < 4; m <<= 1) {
        #pragma unroll
        for (int b = 0; b < 8; ++b) {
            acc0[b] += __shfl_xor(acc0[b], m, 64);
            acc1[b] += __shfl_xor(acc1[b], m, 64);
        }
    }
    if (jq == 0) {
        #pragma unroll
        for (int b = 0; b < 8; ++b) {
            nk16[((size_t)b * S_INN + s) * DD + il]      = (_Float16)acc0[b];
            nk16[((size_t)b * S_INN + s) * DD + il + 64] = (_Float16)acc1[b];
        }
    }
}

// ---------------------------------------------------------------------------
// kXf: transpose+convert f32 (R x C) -> f16 (C x R), 64x64 LDS tiles.
// tile stride 67 (odd dwords) so 16-row column-read groups don't bank-alias.
// ---------------------------------------------------------------------------
__global__ __launch_bounds__(256) void kXf(const float* __restrict__ src,
                                           _Float16* __restrict__ dst,
                                           int R, int C) {
    const size_t sb = (size_t)blockIdx.z * (size_t)R * C;
    const int r0 = blockIdx.x * 64, c0 = blockIdx.y * 64;
    __shared__ float tile[64][67];
    const int tid = threadIdx.x;
    {
        const int lr = tid >> 2, lc = (tid & 3) * 16;
        const float4* srow = (const float4*)&src[sb + (size_t)(r0 + lr) * C + c0 + lc];
        float4 v0 = srow[0], v1 = srow[1], v2 = srow[2], v3 = srow[3];
        *(float4*)&tile[lr][lc +  0] = v0;
        *(float4*)&tile[lr][lc +  4] = v1;
        *(float4*)&tile[lr][lc +  8] = v2;
        *(float4*)&tile[lr][lc + 12] = v3;
    }
    __syncthreads();
    {
        const int wc = tid >> 2, wsx = (tid & 3) * 16;
        h8 o0, o1;
        #pragma unroll
        for (int k = 0; k < 8; ++k) o0[k] = (_Float16)tile[wsx + k][wc];
        #pragma unroll
        for (int k = 0; k < 8; ++k) o1[k] = (_Float16)tile[wsx + 8 + k][wc];
        _Float16* drow = &dst[sb + (size_t)(c0 + wc) * R + r0 + wsx];
        *(h8*)&drow[0] = o0;
        *(h8*)&drow[8] = o1;
    }
}

// ---------------------------------------------------------------------------
// kXh: transpose f16 (R x C) -> f16 (C x R), 64x64 LDS tiles.
// tile stride 74 f16 (odd dwords) to break 16-row bank aliasing.
// ---------------------------------------------------------------------------
__global__ __launch_bounds__(256) void kXh(const _Float16* __restrict__ src,
                                           _Float16* __restrict__ dst,
                                           int R, int C) {
    const size_t sb = (size_t)blockIdx.z * (size_t)R * C;
    const int r0 = blockIdx.x * 64, c0 = blockIdx.y * 64;
    __shared__ _Float16 tile[64][74];
    const int tid = threadIdx.x;
    {
        const int lr = tid >> 2, lc = (tid & 3) * 16;
        const h8* srow = (const h8*)&src[sb + (size_t)(r0 + lr) * C + c0 + lc];
        h8 v0 = srow[0], v1 = srow[1];
        *(h8*)&tile[lr][lc + 0] = v0;
        *(h8*)&tile[lr][lc + 8] = v1;
    }
    __syncthreads();
    {
        const int wc = tid >> 2, wsx = (tid & 3) * 16;
        h8 o0, o1;
        #pragma unroll
        for (int k = 0; k < 8; ++k) o0[k] = tile[wsx + k][wc];
        #pragma unroll
        for (int k = 0; k < 8; ++k) o1[k] = tile[wsx + 8 + k][wc];
        _Float16* drow = &dst[sb + (size_t)(c0 + wc) * R + r0 + wsx];
        *(h8*)&drow[0] = o0;
        *(h8*)&drow[8] = o1;
    }
}

// ---------------------------------------------------------------------------
// Kernel C (MFMA, LDS double-buffered): one GEMM  C[t, b*128+i] over K=s.
//   M=1024 (t, from LT), N=1024 (b*128+i, from NT), K=4096, splitK=4.
// Grid (64, 4): blockIdx.x = mt*8+nt  (mt: t-tile, nt = b), blockIdx.y = kz.
// Block 512 thr = 8 waves (2m x 4n); wave tile 64t x 32n; BK=64.
// LDS 64KB: 2 bufs x (A 128x64 f16 + B 128x64 f16), row-major, XOR-swizzled
//   (byte ^= (row&7)<<4) via pre-swizzled global_load_lds source (rule 21).
// Schedule: T3-minimum {stage(next); compute(cur); __syncthreads()}.
// ---------------------------------------------------------------------------
__global__ __launch_bounds__(512) void kC(const _Float16* __restrict__ NT,
                                          const _Float16* __restrict__ LT,
                                          float* __restrict__ part) {
    __shared__ _Float16 lds_pool[4 * 8192];   // [buf][A|B][128*64]

    const int tid  = threadIdx.x;
    const int lane = tid & 63;
    const int w    = tid >> 6;
    const int wm   = w >> 2;          // 0..1  (t half)
    const int wn   = w & 3;           // 0..3  (n quarter)
    const int lr   = lane & 15;
    const int lh   = lane >> 4;

    const int mt = blockIdx.x >> 3;
    const int nt = blockIdx.x & 7;    // = b
    const int kz = blockIdx.y;
    const int t0 = mt * 128;
    const int n0 = nt * 128;
    const int sbase = kz * 1024;

    const int swz = (lr & 7) << 4;    // byte swizzle for fragment reads

    f32x4 acc[4][2];
    #pragma unroll
    for (int m = 0; m < 4; ++m)
        #pragma unroll
        for (int n = 0; n < 2; ++n) acc[m][n] = (f32x4){0.f, 0.f, 0.f, 0.f};

    // staging: linear LDS dest, inverse-swizzled global source
    auto stage = [&](int buf, int s0) {
        _Float16* base = &lds_pool[buf * 16384];
        #pragma unroll
        for (int ro = 0; ro < 2; ++ro) {
            int idx = tid + ro * 512;          // [0,1024) 16B chunks
            int r   = idx >> 3;                // tile row
            int kb  = idx & 7;                 // 16B block in row
            int skb = kb ^ (r & 7);            // source block (involution)
            gload16(&LT[(size_t)(t0 + r) * S_INN + s0 + skb * 8], base + idx * 8);
            gload16(&NT[(size_t)(n0 + r) * S_INN + s0 + skb * 8], base + 8192 + idx * 8);
        }
    };

    auto compute = [&](int buf) {
        const char* ldsA = (const char*)&lds_pool[buf * 16384];
        const char* ldsB = ldsA + 16384;
        #pragma unroll
        for (int kk = 0; kk < 2; ++kk) {
            const int kb = (kk * 64 + lh * 16) ^ swz;
            h8 a[4], bf[2];
            #pragma unroll
            for (int m = 0; m < 4; ++m)
                a[m] = *(const h8*)(ldsA + (wm * 64 + m * 16 + lr) * 128 + kb);
            #pragma unroll
            for (int n = 0; n < 2; ++n)
                bf[n] = *(const h8*)(ldsB + (wn * 32 + n * 16 + lr) * 128 + kb);
            #pragma unroll
            for (int m = 0; m < 4; ++m)
                #pragma unroll
                for (int n = 0; n < 2; ++n)
                    acc[m][n] = __builtin_amdgcn_mfma_f32_16x16x32_f16(a[m], bf[n], acc[m][n], 0, 0, 0);
        }
    };

    stage(0, sbase);
    __syncthreads();
    for (int st = 0; st < 16; ++st) {
        const int cur = st & 1;
        if (st < 15) stage(cur ^ 1, sbase + (st + 1) * 64);
        compute(cur);
        __syncthreads();
    }

    // epilogue: C[t, n] -> part[kz][b][t][i];  C map: col=lr (n), row=lh*4+reg (t)
    float* dst = &part[(size_t)(kz * B_SZ + nt) * S_OUTT * DD];
    #pragma unroll
    for (int m = 0; m < 4; ++m) {
        const int t = t0 + wm * 64 + m * 16 + lh * 4;
        #pragma unroll
        for (int n = 0; n < 2; ++n) {
            const int i = wn * 32 + n * 16 + lr;
            #pragma unroll
            for (int r = 0; r < 4; ++r)
                dst[(size_t)(t + r) * DD + i] = acc[m][n][r];
        }
    }
}

// ---------------------------------------------------------------------------
// Kernel D: out = sum of the 4 K-split partials
// ---------------------------------------------------------------------------
__global__ __launch_bounds__(256) void kD(const float* __restrict__ part,
                                          float* __restrict__ out) {
    const int e4 = blockIdx.x * 256 + threadIdx.x;
    const float4* p = (const float4*)part;
    float4 a  = p[e4];
    float4 b1 = p[e4 + 262144];
    float4 c1 = p[e4 + 2 * 262144];
    float4 d1 = p[e4 + 3 * 262144];
    float4 o;
    o.x = a.x + b1.x + c1.x + d1.x;
    o.y = a.y + b1.y + c1.y + d1.y;
    o.z = a.z + b1.z + c1.z + d1.z;
    o.w = a.w + b1.w + c1.w + d1.w;
    ((float4*)out)[e4] = o;
}

extern "C" void kernel_launch(void* const* d_in, const int* in_sizes, int n_in,
                              void* d_out, int out_size, void* d_ws, size_t ws_size,
                              hipStream_t stream) {
    const float* x     = (const float*)d_in[0];
    const float* M     = (const float*)d_in[1];
    const float* P     = (const float*)d_in[2];
    const float* Lk    = (const float*)d_in[3];
    const float* gamma = (const float*)d_in[4];
    const float* beta  = (const float*)d_in[5];
    float* out = (float*)d_out;

    float* wsf = (float*)d_ws;
    float*     xn   = wsf + XN_OFF;                 // f32 (B,S,D)
    _Float16*  nk16 = (_Float16*)(wsf + NK16_OFF);  // f16 (B,S,D)
    _Float16*  NT   = (_Float16*)(wsf + NT_OFF);    // f16 (B,D,S)
    _Float16*  LT   = (_Float16*)(wsf + LT_OFF);    // f16 (T,S)
    float*     part = wsf + XN_OFF;                 // reuse xn region

    hipLaunchKernelGGL(kA,  dim3(256),        dim3(256), 0, stream, x, M, gamma, beta, xn);
    hipLaunchKernelGGL(kB,  dim3(4096),       dim3(256), 0, stream, xn, P, nk16);
    hipLaunchKernelGGL(kXh, dim3(64, 2, 8),   dim3(256), 0, stream, nk16, NT, S_INN, DD);
    hipLaunchKernelGGL(kXf, dim3(64, 16, 1),  dim3(256), 0, stream, Lk, LT, S_INN, S_OUTT);
    hipLaunchKernelGGL(kC,  dim3(64, 4),      dim3(512), 0, stream, NT, LT, part);
    hipLaunchKernelGGL(kD,  dim3(1024),       dim3(256), 0, stream, part, out);
}

// Round 6
// 176.678 us; speedup vs baseline: 1.3533x; 1.0425x over previous
//
#include <hip/hip_runtime.h>
#include <math.h>

#define B_SZ   8
#define S_INN  4096
#define S_OUTT 1024
#define DD     128
#define EPS_LN 1e-5f

typedef _Float16 h2 __attribute__((ext_vector_type(2)));
typedef _Float16 h4 __attribute__((ext_vector_type(4)));
typedef _Float16 h8 __attribute__((ext_vector_type(8)));
typedef float f32x4 __attribute__((ext_vector_type(4)));

// ws layout (float offsets):
//   xn16  [0, ...)              f16  (B,S,D)   dead after kB -> region reused by part (16MB)
//   Nk16  [4194304,  6291456)   f16  (B,S,D)
//   NT    [6291456,  8388608)   f16  (B,D,S)   = Nk16 transposed  (= B-matrix [b*128+i][s])
//   LT    [8388608, 10485760)   f16  (T,S)     = Linker transposed
#define XN_OFF   0
#define NK16_OFF 4194304
#define NT_OFF   6291456
#define LT_OFF   8388608

__device__ __forceinline__ void gload16(const void* g, void* l) {
    __builtin_amdgcn_global_load_lds(
        (const __attribute__((address_space(1))) unsigned int*)g,
        (__attribute__((address_space(3))) unsigned int*)l, 16, 0, 0);
}

__device__ __forceinline__ float fdot2_(h2 a, h2 b, float c) {
#if __has_builtin(__builtin_amdgcn_fdot2)
    return __builtin_amdgcn_fdot2(a, b, c, false);
#else
    return fmaf((float)a[0], (float)b[0], fmaf((float)a[1], (float)b[1], c));
#endif
}

// ---------------------------------------------------------------------------
// Kernel A: xn16 = (f16) [ LayerNorm(x @ M^T) * gamma + beta ]
// 512 blocks x 256 thr; 64 rows/block (2 blocks/CU); thread=(ig in [0,8),
// rg in [0,32)) computes 2 rows x 16 cols. M staged in LDS interleave-swizzled.
// ---------------------------------------------------------------------------
__global__ __launch_bounds__(256) void kA(const float* __restrict__ x,
                                          const float* __restrict__ M,
                                          const float* __restrict__ gamma,
                                          const float* __restrict__ beta,
                                          _Float16* __restrict__ xn16) {
    __shared__ float Ms[128 * 128];

    const int tid = threadIdx.x;
    #pragma unroll
    for (int k = 0; k < 16; ++k) {
        int e4 = tid + k * 256;
        int i  = e4 >> 5;
        int j4 = e4 & 31;
        float4 v = *(const float4*)&M[i * DD + j4 * 4];
        int igp = (i >> 4) & 7;
        int qp  = (i >> 2) & 3;
        int cp  = i & 3;
        int col = (qp * 8 + igp) * 4 + cp;
        Ms[(j4 * 4 + 0) * 128 + col] = v.x;
        Ms[(j4 * 4 + 1) * 128 + col] = v.y;
        Ms[(j4 * 4 + 2) * 128 + col] = v.z;
        Ms[(j4 * 4 + 3) * 128 + col] = v.w;
    }
    __syncthreads();

    const int ig = tid & 7;
    const int rg = tid >> 3;
    const int row0 = blockIdx.x * 64 + rg * 2;

    float acc[2][16];
    #pragma unroll
    for (int rr = 0; rr < 2; ++rr)
        #pragma unroll
        for (int k = 0; k < 16; ++k) acc[rr][k] = 0.f;

    const float4* xr[2];
    #pragma unroll
    for (int rr = 0; rr < 2; ++rr) xr[rr] = (const float4*)&x[(size_t)(row0 + rr) * DD];

    for (int j4 = 0; j4 < 32; ++j4) {
        float xvf[2][4];
        #pragma unroll
        for (int rr = 0; rr < 2; ++rr) {
            float4 t = xr[rr][j4];
            xvf[rr][0] = t.x; xvf[rr][1] = t.y; xvf[rr][2] = t.z; xvf[rr][3] = t.w;
        }
        #pragma unroll
        for (int c = 0; c < 4; ++c) {
            const float* Mrow = &Ms[(j4 * 4 + c) * 128];
            #pragma unroll
            for (int q = 0; q < 4; ++q) {
                const float4 mv = *(const float4*)&Mrow[(q * 8 + ig) * 4];
                #pragma unroll
                for (int rr = 0; rr < 2; ++rr) {
                    acc[rr][q * 4 + 0] = fmaf(xvf[rr][c], mv.x, acc[rr][q * 4 + 0]);
                    acc[rr][q * 4 + 1] = fmaf(xvf[rr][c], mv.y, acc[rr][q * 4 + 1]);
                    acc[rr][q * 4 + 2] = fmaf(xvf[rr][c], mv.z, acc[rr][q * 4 + 2]);
                    acc[rr][q * 4 + 3] = fmaf(xvf[rr][c], mv.w, acc[rr][q * 4 + 3]);
                }
            }
        }
    }

    float g[16], be[16];
    #pragma unroll
    for (int q = 0; q < 4; ++q) {
        float4 gv = *(const float4*)&gamma[ig * 16 + q * 4];
        float4 bv = *(const float4*)&beta[ig * 16 + q * 4];
        g[q*4+0]=gv.x; g[q*4+1]=gv.y; g[q*4+2]=gv.z; g[q*4+3]=gv.w;
        be[q*4+0]=bv.x; be[q*4+1]=bv.y; be[q*4+2]=bv.z; be[q*4+3]=bv.w;
    }
    #pragma unroll
    for (int rr = 0; rr < 2; ++rr) {
        float s1 = 0.f, s2 = 0.f;
        #pragma unroll
        for (int k = 0; k < 16; ++k) { s1 += acc[rr][k]; s2 = fmaf(acc[rr][k], acc[rr][k], s2); }
        #pragma unroll
        for (int m = 1; m < 8; m <<= 1) {
            s1 += __shfl_xor(s1, m, 64);
            s2 += __shfl_xor(s2, m, 64);
        }
        float mu  = s1 * (1.f / 128.f);
        float var = s2 * (1.f / 128.f) - mu * mu;
        float rstd = rsqrtf(var + EPS_LN);
        _Float16* dst = &xn16[(size_t)(row0 + rr) * DD + ig * 16];
        #pragma unroll
        for (int q = 0; q < 4; ++q) {
            h4 hv;
            hv[0] = (_Float16)((acc[rr][q*4+0] - mu) * rstd * g[q*4+0] + be[q*4+0]);
            hv[1] = (_Float16)((acc[rr][q*4+1] - mu) * rstd * g[q*4+1] + be[q*4+1]);
            hv[2] = (_Float16)((acc[rr][q*4+2] - mu) * rstd * g[q*4+2] + be[q*4+2]);
            hv[3] = (_Float16)((acc[rr][q*4+3] - mu) * rstd * g[q*4+3] + be[q*4+3]);
            *(h4*)&dst[q * 4] = hv;
        }
    }
}

// ---------------------------------------------------------------------------
// Kernel B: Nk16[b,s,i] = (f16) sum_j xn[b,s,j] * P[i,j] * cos(2*pi*s/(i*128+j+2))
// grid 4096 (one per s) x 256 thr; thread=(il=tid>>2, jq=tid&3): i in {il,il+64},
// j in [jq*32,+32). v_dot2_f32_f16 over (j-pair, batch) with f32 accumulators.
// LDS 37KB (Ps f16 pad-136 + xs slot-permuted [j2][b][2]) -> 4 blocks/CU.
// phi via exact int-mod + v_cos (revolutions; cos even+periodic, no fract).
// ---------------------------------------------------------------------------
__global__ __launch_bounds__(256, 4) void kB(const _Float16* __restrict__ xn16,
                                             const float* __restrict__ P,
                                             _Float16* __restrict__ nk16) {
    const int s = blockIdx.x;
    __shared__ _Float16 Ps[128 * 136];          // 34.8 KB, 16B-aligned rows
    __shared__ _Float16 xs[64 * 16];            // 2 KB: [slot][b][2]

    const int tid = threadIdx.x;
    {   // stage xs: slot(j2) = (j2&15)*4 + (j2>>4) so jq-groups hit distinct banks
        int j  = tid & 127;
        int bh = (tid >> 7) * 4;
        int j2 = j >> 1;
        int slot = (j2 & 15) * 4 + (j2 >> 4);
        #pragma unroll
        for (int bo = 0; bo < 4; ++bo) {
            int b = bh + bo;
            xs[slot * 16 + b * 2 + (j & 1)] = xn16[((size_t)b * S_INN + s) * DD + j];
        }
    }
    #pragma unroll
    for (int k = 0; k < 16; ++k) {
        int e4 = tid + k * 256;
        int ip = e4 >> 5, j4 = e4 & 31;
        float4 v = *(const float4*)&P[ip * DD + j4 * 4];
        h4 hv = { (_Float16)v.x, (_Float16)v.y, (_Float16)v.z, (_Float16)v.w };
        *(h4*)&Ps[ip * 136 + j4 * 4] = hv;
    }
    __syncthreads();

    const int il = tid >> 2;           // [0,64)
    const int jq = tid & 3;            // [0,4)
    const float kf = (float)s;
    const float pb0 = (float)(il * DD + jq * 32 + 2);

    float acc0[8] = {0.f,0.f,0.f,0.f,0.f,0.f,0.f,0.f};
    float acc1[8] = {0.f,0.f,0.f,0.f,0.f,0.f,0.f,0.f};

    #pragma unroll
    for (int j8 = 0; j8 < 4; ++j8) {
        const int j0 = jq * 32 + j8 * 8;
        h8 p0 = *(const h8*)&Ps[il * 136 + j0];
        h8 p1 = *(const h8*)&Ps[(il + 64) * 136 + j0];

        h2 w0[4], w1[4];
        #pragma unroll
        for (int cp = 0; cp < 4; ++cp) {
            float wv0[2], wv1[2];
            #pragma unroll
            for (int u = 0; u < 2; ++u) {
                int c = cp * 2 + u;
                float pf0 = pb0 + (float)(j8 * 8 + c);
                float iv0 = __builtin_amdgcn_rcpf(pf0);
                float q0  = floorf(kf * iv0);
                float rm0 = fmaf(-q0, pf0, kf);          // exact (ints < 2^24)
                wv0[u] = (float)p0[c] * __builtin_amdgcn_cosf(rm0 * iv0);
                float pf1 = pf0 + 8192.f;                // (il+64)*128
                float iv1 = __builtin_amdgcn_rcpf(pf1);
                float q1  = floorf(kf * iv1);
                float rm1 = fmaf(-q1, pf1, kf);
                wv1[u] = (float)p1[c] * __builtin_amdgcn_cosf(rm1 * iv1);
            }
            w0[cp] = h2{ (_Float16)wv0[0], (_Float16)wv0[1] };
            w1[cp] = h2{ (_Float16)wv1[0], (_Float16)wv1[1] };
        }

        #pragma unroll
        for (int jp = 0; jp < 4; ++jp) {
            int slot = (j8 * 4 + jp) * 4 + jq;           // = (j2&15)*4 + (j2>>4)
            const h8 xlo = *(const h8*)&xs[slot * 16];       // b0..3 pairs
            const h8 xhi = *(const h8*)&xs[slot * 16 + 8];   // b4..7 pairs
            #pragma unroll
            for (int b = 0; b < 4; ++b) {
                h2 xa = h2{ xlo[b * 2], xlo[b * 2 + 1] };
                h2 xb = h2{ xhi[b * 2], xhi[b * 2 + 1] };
                acc0[b]     = fdot2_(w0[jp], xa, acc0[b]);
                acc0[b + 4] = fdot2_(w0[jp], xb, acc0[b + 4]);
                acc1[b]     = fdot2_(w1[jp], xa, acc1[b]);
                acc1[b + 4] = fdot2_(w1[jp], xb, acc1[b + 4]);
            }
        }
    }

    #pragma unroll
    for (int m = 1; m < 4; m <<= 1) {
        #pragma unroll
        for (int b = 0; b < 8; ++b) {
            acc0[b] += __shfl_xor(acc0[b], m, 64);
            acc1[b] += __shfl_xor(acc1[b], m, 64);
        }
    }
    if (jq == 0) {
        #pragma unroll
        for (int b = 0; b < 8; ++b) {
            nk16[((size_t)b * S_INN + s) * DD + il]      = (_Float16)acc0[b];
            nk16[((size_t)b * S_INN + s) * DD + il + 64] = (_Float16)acc1[b];
        }
    }
}

// ---------------------------------------------------------------------------
// kXf: transpose+convert f32 (R x C) -> f16 (C x R), 64x64 LDS tiles.
// ---------------------------------------------------------------------------
__global__ __launch_bounds__(256) void kXf(const float* __restrict__ src,
                                           _Float16* __restrict__ dst,
                                           int R, int C) {
    const size_t sb = (size_t)blockIdx.z * (size_t)R * C;
    const int r0 = blockIdx.x * 64, c0 = blockIdx.y * 64;
    __shared__ float tile[64][67];
    const int tid = threadIdx.x;
    {
        const int lr = tid >> 2, lc = (tid & 3) * 16;
        const float4* srow = (const float4*)&src[sb + (size_t)(r0 + lr) * C + c0 + lc];
        float4 v0 = srow[0], v1 = srow[1], v2 = srow[2], v3 = srow[3];
        *(float4*)&tile[lr][lc +  0] = v0;
        *(float4*)&tile[lr][lc +  4] = v1;
        *(float4*)&tile[lr][lc +  8] = v2;
        *(float4*)&tile[lr][lc + 12] = v3;
    }
    __syncthreads();
    {
        const int wc = tid >> 2, wsx = (tid & 3) * 16;
        h8 o0, o1;
        #pragma unroll
        for (int k = 0; k < 8; ++k) o0[k] = (_Float16)tile[wsx + k][wc];
        #pragma unroll
        for (int k = 0; k < 8; ++k) o1[k] = (_Float16)tile[wsx + 8 + k][wc];
        _Float16* drow = &dst[sb + (size_t)(c0 + wc) * R + r0 + wsx];
        *(h8*)&drow[0] = o0;
        *(h8*)&drow[8] = o1;
    }
}

// ---------------------------------------------------------------------------
// kXh: transpose f16 (R x C) -> f16 (C x R), 64x64 LDS tiles.
// ---------------------------------------------------------------------------
__global__ __launch_bounds__(256) void kXh(const _Float16* __restrict__ src,
                                           _Float16* __restrict__ dst,
                                           int R, int C) {
    const size_t sb = (size_t)blockIdx.z * (size_t)R * C;
    const int r0 = blockIdx.x * 64, c0 = blockIdx.y * 64;
    __shared__ _Float16 tile[64][74];
    const int tid = threadIdx.x;
    {
        const int lr = tid >> 2, lc = (tid & 3) * 16;
        const h8* srow = (const h8*)&src[sb + (size_t)(r0 + lr) * C + c0 + lc];
        h8 v0 = srow[0], v1 = srow[1];
        *(h8*)&tile[lr][lc + 0] = v0;
        *(h8*)&tile[lr][lc + 8] = v1;
    }
    __syncthreads();
    {
        const int wc = tid >> 2, wsx = (tid & 3) * 16;
        h8 o0, o1;
        #pragma unroll
        for (int k = 0; k < 8; ++k) o0[k] = tile[wsx + k][wc];
        #pragma unroll
        for (int k = 0; k < 8; ++k) o1[k] = tile[wsx + 8 + k][wc];
        _Float16* drow = &dst[sb + (size_t)(c0 + wc) * R + r0 + wsx];
        *(h8*)&drow[0] = o0;
        *(h8*)&drow[8] = o1;
    }
}

// ---------------------------------------------------------------------------
// Kernel C (MFMA, LDS double-buffered): one GEMM  C[t, b*128+i] over K=s.
// Grid (64, 4); 512 thr = 8 waves (2m x 4n); wave tile 64t x 32n; BK=64.
// LDS 64KB: 2 bufs x (A+B 128x64 f16), XOR-swizzled via pre-swizzled source.
// ---------------------------------------------------------------------------
__global__ __launch_bounds__(512) void kC(const _Float16* __restrict__ NT,
                                          const _Float16* __restrict__ LT,
                                          float* __restrict__ part) {
    __shared__ _Float16 lds_pool[4 * 8192];   // [buf][A|B][128*64]

    const int tid  = threadIdx.x;
    const int lane = tid & 63;
    const int w    = tid >> 6;
    const int wm   = w >> 2;
    const int wn   = w & 3;
    const int lr   = lane & 15;
    const int lh   = lane >> 4;

    const int mt = blockIdx.x >> 3;
    const int nt = blockIdx.x & 7;    // = b
    const int kz = blockIdx.y;
    const int t0 = mt * 128;
    const int n0 = nt * 128;
    const int sbase = kz * 1024;

    const int swz = (lr & 7) << 4;

    f32x4 acc[4][2];
    #pragma unroll
    for (int m = 0; m < 4; ++m)
        #pragma unroll
        for (int n = 0; n < 2; ++n) acc[m][n] = (f32x4){0.f, 0.f, 0.f, 0.f};

    auto stage = [&](int buf, int s0) {
        _Float16* base = &lds_pool[buf * 16384];
        #pragma unroll
        for (int ro = 0; ro < 2; ++ro) {
            int idx = tid + ro * 512;
            int r   = idx >> 3;
            int kb  = idx & 7;
            int skb = kb ^ (r & 7);
            gload16(&LT[(size_t)(t0 + r) * S_INN + s0 + skb * 8], base + idx * 8);
            gload16(&NT[(size_t)(n0 + r) * S_INN + s0 + skb * 8], base + 8192 + idx * 8);
        }
    };

    auto compute = [&](int buf) {
        const char* ldsA = (const char*)&lds_pool[buf * 16384];
        const char* ldsB = ldsA + 16384;
        #pragma unroll
        for (int kk = 0; kk < 2; ++kk) {
            const int kb = (kk * 64 + lh * 16) ^ swz;
            h8 a[4], bf[2];
            #pragma unroll
            for (int m = 0; m < 4; ++m)
                a[m] = *(const h8*)(ldsA + (wm * 64 + m * 16 + lr) * 128 + kb);
            #pragma unroll
            for (int n = 0; n < 2; ++n)
                bf[n] = *(const h8*)(ldsB + (wn * 32 + n * 16 + lr) * 128 + kb);
            #pragma unroll
            for (int m = 0; m < 4; ++m)
                #pragma unroll
                for (int n = 0; n < 2; ++n)
                    acc[m][n] = __builtin_amdgcn_mfma_f32_16x16x32_f16(a[m], bf[n], acc[m][n], 0, 0, 0);
        }
    };

    stage(0, sbase);
    __syncthreads();
    for (int st = 0; st < 16; ++st) {
        const int cur = st & 1;
        if (st < 15) stage(cur ^ 1, sbase + (st + 1) * 64);
        compute(cur);
        __syncthreads();
    }

    float* dst = &part[(size_t)(kz * B_SZ + nt) * S_OUTT * DD];
    #pragma unroll
    for (int m = 0; m < 4; ++m) {
        const int t = t0 + wm * 64 + m * 16 + lh * 4;
        #pragma unroll
        for (int n = 0; n < 2; ++n) {
            const int i = wn * 32 + n * 16 + lr;
            #pragma unroll
            for (int r = 0; r < 4; ++r)
                dst[(size_t)(t + r) * DD + i] = acc[m][n][r];
        }
    }
}

// ---------------------------------------------------------------------------
// Kernel D: out = sum of the 4 K-split partials
// ---------------------------------------------------------------------------
__global__ __launch_bounds__(256) void kD(const float* __restrict__ part,
                                          float* __restrict__ out) {
    const int e4 = blockIdx.x * 256 + threadIdx.x;
    const float4* p = (const float4*)part;
    float4 a  = p[e4];
    float4 b1 = p[e4 + 262144];
    float4 c1 = p[e4 + 2 * 262144];
    float4 d1 = p[e4 + 3 * 262144];
    float4 o;
    o.x = a.x + b1.x + c1.x + d1.x;
    o.y = a.y + b1.y + c1.y + d1.y;
    o.z = a.z + b1.z + c1.z + d1.z;
    o.w = a.w + b1.w + c1.w + d1.w;
    ((float4*)out)[e4] = o;
}

extern "C" void kernel_launch(void* const* d_in, const int* in_sizes, int n_in,
                              void* d_out, int out_size, void* d_ws, size_t ws_size,
                              hipStream_t stream) {
    const float* x     = (const float*)d_in[0];
    const float* M     = (const float*)d_in[1];
    const float* P     = (const float*)d_in[2];
    const float* Lk    = (const float*)d_in[3];
    const float* gamma = (const float*)d_in[4];
    const float* beta  = (const float*)d_in[5];
    float* out = (float*)d_out;

    float* wsf = (float*)d_ws;
    _Float16*  xn16 = (_Float16*)(wsf + XN_OFF);    // f16 (B,S,D), dead after kB
    _Float16*  nk16 = (_Float16*)(wsf + NK16_OFF);  // f16 (B,S,D)
    _Float16*  NT   = (_Float16*)(wsf + NT_OFF);    // f16 (B,D,S)
    _Float16*  LT   = (_Float16*)(wsf + LT_OFF);    // f16 (T,S)
    float*     part = wsf + XN_OFF;                 // reuse xn region

    hipLaunchKernelGGL(kA,  dim3(512),        dim3(256), 0, stream, x, M, gamma, beta, xn16);
    hipLaunchKernelGGL(kB,  dim3(4096),       dim3(256), 0, stream, xn16, P, nk16);
    hipLaunchKernelGGL(kXh, dim3(64, 2, 8),   dim3(256), 0, stream, nk16, NT, S_INN, DD);
    hipLaunchKernelGGL(kXf, dim3(64, 16, 1),  dim3(256), 0, stream, Lk, LT, S_INN, S_OUTT);
    hipLaunchKernelGGL(kC,  dim3(64, 4),      dim3(512), 0, stream, NT, LT, part);
    hipLaunchKernelGGL(kD,  dim3(1024),       dim3(256), 0, stream, part, out);
}

// Round 7
// 169.013 us; speedup vs baseline: 1.4147x; 1.0454x over previous
//
#include <hip/hip_runtime.h>
#include <math.h>

#define B_SZ   8
#define S_INN  4096
#define S_OUTT 1024
#define DD     128
#define EPS_LN 1e-5f

typedef _Float16 h2 __attribute__((ext_vector_type(2)));
typedef _Float16 h4 __attribute__((ext_vector_type(4)));
typedef _Float16 h8 __attribute__((ext_vector_type(8)));
typedef float f32x4 __attribute__((ext_vector_type(4)));

// ws layout (float offsets):
//   xn16  [0, ...)              f16  (B,S,D)   dead after kB -> region reused by part (16MB)
//   NT    [6291456,  8388608)   f16  (B,D,S)   (= GEMM B-matrix [b*128+i][s]) written by kB
//   LT    [8388608, 10485760)   f16  (T,S)     = Linker transposed
#define XN_OFF   0
#define NT_OFF   6291456
#define LT_OFF   8388608

__device__ __forceinline__ void gload16(const void* g, void* l) {
    __builtin_amdgcn_global_load_lds(
        (const __attribute__((address_space(1))) unsigned int*)g,
        (__attribute__((address_space(3))) unsigned int*)l, 16, 0, 0);
}

__device__ __forceinline__ float fdot2_(h2 a, h2 b, float c) {
#if __has_builtin(__builtin_amdgcn_fdot2)
    return __builtin_amdgcn_fdot2(a, b, c, false);
#else
    return fmaf((float)a[0], (float)b[0], fmaf((float)a[1], (float)b[1], c));
#endif
}

__device__ __forceinline__ float fract_(float x) {
#if __has_builtin(__builtin_amdgcn_fractf)
    return __builtin_amdgcn_fractf(x);
#else
    return x - floorf(x);
#endif
}

// ---------------------------------------------------------------------------
// Kernel A: xn16 = (f16) [ LayerNorm(x @ M^T) * gamma + beta ]
// 512 blocks x 256 thr; 64 rows/block; thread computes 2 rows x 16 cols.
// ---------------------------------------------------------------------------
__global__ __launch_bounds__(256) void kA(const float* __restrict__ x,
                                          const float* __restrict__ M,
                                          const float* __restrict__ gamma,
                                          const float* __restrict__ beta,
                                          _Float16* __restrict__ xn16) {
    __shared__ float Ms[128 * 128];

    const int tid = threadIdx.x;
    #pragma unroll
    for (int k = 0; k < 16; ++k) {
        int e4 = tid + k * 256;
        int i  = e4 >> 5;
        int j4 = e4 & 31;
        float4 v = *(const float4*)&M[i * DD + j4 * 4];
        int igp = (i >> 4) & 7;
        int qp  = (i >> 2) & 3;
        int cp  = i & 3;
        int col = (qp * 8 + igp) * 4 + cp;
        Ms[(j4 * 4 + 0) * 128 + col] = v.x;
        Ms[(j4 * 4 + 1) * 128 + col] = v.y;
        Ms[(j4 * 4 + 2) * 128 + col] = v.z;
        Ms[(j4 * 4 + 3) * 128 + col] = v.w;
    }
    __syncthreads();

    const int ig = tid & 7;
    const int rg = tid >> 3;
    const int row0 = blockIdx.x * 64 + rg * 2;

    float acc[2][16];
    #pragma unroll
    for (int rr = 0; rr < 2; ++rr)
        #pragma unroll
        for (int k = 0; k < 16; ++k) acc[rr][k] = 0.f;

    const float4* xr[2];
    #pragma unroll
    for (int rr = 0; rr < 2; ++rr) xr[rr] = (const float4*)&x[(size_t)(row0 + rr) * DD];

    for (int j4 = 0; j4 < 32; ++j4) {
        float xvf[2][4];
        #pragma unroll
        for (int rr = 0; rr < 2; ++rr) {
            float4 t = xr[rr][j4];
            xvf[rr][0] = t.x; xvf[rr][1] = t.y; xvf[rr][2] = t.z; xvf[rr][3] = t.w;
        }
        #pragma unroll
        for (int c = 0; c < 4; ++c) {
            const float* Mrow = &Ms[(j4 * 4 + c) * 128];
            #pragma unroll
            for (int q = 0; q < 4; ++q) {
                const float4 mv = *(const float4*)&Mrow[(q * 8 + ig) * 4];
                #pragma unroll
                for (int rr = 0; rr < 2; ++rr) {
                    acc[rr][q * 4 + 0] = fmaf(xvf[rr][c], mv.x, acc[rr][q * 4 + 0]);
                    acc[rr][q * 4 + 1] = fmaf(xvf[rr][c], mv.y, acc[rr][q * 4 + 1]);
                    acc[rr][q * 4 + 2] = fmaf(xvf[rr][c], mv.z, acc[rr][q * 4 + 2]);
                    acc[rr][q * 4 + 3] = fmaf(xvf[rr][c], mv.w, acc[rr][q * 4 + 3]);
                }
            }
        }
    }

    float g[16], be[16];
    #pragma unroll
    for (int q = 0; q < 4; ++q) {
        float4 gv = *(const float4*)&gamma[ig * 16 + q * 4];
        float4 bv = *(const float4*)&beta[ig * 16 + q * 4];
        g[q*4+0]=gv.x; g[q*4+1]=gv.y; g[q*4+2]=gv.z; g[q*4+3]=gv.w;
        be[q*4+0]=bv.x; be[q*4+1]=bv.y; be[q*4+2]=bv.z; be[q*4+3]=bv.w;
    }
    #pragma unroll
    for (int rr = 0; rr < 2; ++rr) {
        float s1 = 0.f, s2 = 0.f;
        #pragma unroll
        for (int k = 0; k < 16; ++k) { s1 += acc[rr][k]; s2 = fmaf(acc[rr][k], acc[rr][k], s2); }
        #pragma unroll
        for (int m = 1; m < 8; m <<= 1) {
            s1 += __shfl_xor(s1, m, 64);
            s2 += __shfl_xor(s2, m, 64);
        }
        float mu  = s1 * (1.f / 128.f);
        float var = s2 * (1.f / 128.f) - mu * mu;
        float rstd = rsqrtf(var + EPS_LN);
        _Float16* dst = &xn16[(size_t)(row0 + rr) * DD + ig * 16];
        #pragma unroll
        for (int q = 0; q < 4; ++q) {
            h4 hv;
            hv[0] = (_Float16)((acc[rr][q*4+0] - mu) * rstd * g[q*4+0] + be[q*4+0]);
            hv[1] = (_Float16)((acc[rr][q*4+1] - mu) * rstd * g[q*4+1] + be[q*4+1]);
            hv[2] = (_Float16)((acc[rr][q*4+2] - mu) * rstd * g[q*4+2] + be[q*4+2]);
            hv[3] = (_Float16)((acc[rr][q*4+3] - mu) * rstd * g[q*4+3] + be[q*4+3]);
            *(h4*)&dst[q * 4] = hv;
        }
    }
}

// ---------------------------------------------------------------------------
// Kernel B (s-tiled): NT[b*128+i][s] = (f16) sum_j xn[b,s,j]*P[i,j]*cos_rev(s/(i*128+j+2))
// grid 512 (8 s each) x 256 thr; thread = (il=tid>>2, jq=tid&3): i in {il,il+64},
// j in [jq*32,+32), all 8 s. phi = cos_rev(fract(s*rcp(p))) — uniform, no mod.
// xs slot-permuted so the 4 jq groups read disjoint bank octets (il broadcast).
// Reduce-scatter over the 4 jq lanes -> each lane owns 2 b; h8 NT stores
// (s-contiguous) replace the separate kXh transpose kernel entirely.
// ---------------------------------------------------------------------------
__global__ __launch_bounds__(256) void kB(const _Float16* __restrict__ xn16,
                                          const float* __restrict__ P,
                                          _Float16* __restrict__ NT) {
    const int s0 = blockIdx.x * 8;
    __shared__ _Float16 Ps[128 * 136];     // 34.8 KB
    __shared__ _Float16 xs[8 * 1024];      // 16 KB: [s][slot(j2)][b][2]

    const int tid = threadIdx.x;
    // stage xs: 1024 chunks of 8 f16
    #pragma unroll
    for (int k = 0; k < 4; ++k) {
        int c   = tid + k * 256;
        int row = c >> 4;                  // b = row>>3, sl = row&7
        int b   = row >> 3, sl = row & 7;
        int kk  = c & 15;                  // j = kk*8
        h8 v = *(const h8*)&xn16[((size_t)b * S_INN + s0 + sl) * DD + kk * 8];
        #pragma unroll
        for (int q = 0; q < 4; ++q) {
            int j2 = kk * 4 + q;
            int slot = (j2 & 15) * 4 + (j2 >> 4);
            *(h2*)&xs[sl * 1024 + slot * 16 + b * 2] = h2{ v[q * 2], v[q * 2 + 1] };
        }
    }
    // stage Ps (f32 -> f16)
    #pragma unroll
    for (int k = 0; k < 16; ++k) {
        int e4 = tid + k * 256;
        int ip = e4 >> 5, j4 = e4 & 31;
        float4 v = *(const float4*)&P[ip * DD + j4 * 4];
        *(h4*)&Ps[ip * 136 + j4 * 4] = h4{ (_Float16)v.x, (_Float16)v.y,
                                           (_Float16)v.z, (_Float16)v.w };
    }
    __syncthreads();

    const int il = tid >> 2;
    const int jq = tid & 3;
    const int j0base = jq * 32;
    const float s0f = (float)s0;
    const float pb0 = (float)(il * DD + j0base + 2);      // p base, i = il
    const int bsel = ((jq & 1) << 2) | (jq & 2);          // owned b-pair base

    h8 st[4];                                             // [ih*2+k] packs 8 s
    #pragma unroll
    for (int s_ = 0; s_ < 4; ++s_) st[s_] = h8{};

    #pragma unroll
    for (int sl = 0; sl < 8; ++sl) {
        const float sf = s0f + (float)sl;
        float acc0[8] = {0,0,0,0,0,0,0,0};
        float acc1[8] = {0,0,0,0,0,0,0,0};

        #pragma unroll
        for (int j8 = 0; j8 < 4; ++j8) {
            h8 p0 = *(const h8*)&Ps[il * 136 + j0base + j8 * 8];
            h8 p1 = *(const h8*)&Ps[(il + 64) * 136 + j0base + j8 * 8];

            h2 w0[4], w1[4];
            #pragma unroll
            for (int cp = 0; cp < 4; ++cp) {
                float wv0[2], wv1[2];
                #pragma unroll
                for (int u = 0; u < 2; ++u) {
                    int c = cp * 2 + u;
                    float pf0 = pb0 + (float)(j8 * 8 + c);
                    float r0  = fract_(sf * __builtin_amdgcn_rcpf(pf0));
                    wv0[u] = (float)p0[c] * __builtin_amdgcn_cosf(r0);
                    float pf1 = pf0 + 8192.f;             // (il+64)*128
                    float r1  = fract_(sf * __builtin_amdgcn_rcpf(pf1));
                    wv1[u] = (float)p1[c] * __builtin_amdgcn_cosf(r1);
                }
                w0[cp] = h2{ (_Float16)wv0[0], (_Float16)wv0[1] };
                w1[cp] = h2{ (_Float16)wv1[0], (_Float16)wv1[1] };
            }

            #pragma unroll
            for (int jp = 0; jp < 4; ++jp) {
                int slot = (j8 * 4 + jp) * 4 + jq;
                const h8 xlo = *(const h8*)&xs[sl * 1024 + slot * 16];
                const h8 xhi = *(const h8*)&xs[sl * 1024 + slot * 16 + 8];
                #pragma unroll
                for (int b = 0; b < 4; ++b) {
                    h2 xa = h2{ xlo[b * 2], xlo[b * 2 + 1] };
                    h2 xb = h2{ xhi[b * 2], xhi[b * 2 + 1] };
                    acc0[b]     = fdot2_(w0[jp], xa, acc0[b]);
                    acc0[b + 4] = fdot2_(w0[jp], xb, acc0[b + 4]);
                    acc1[b]     = fdot2_(w1[jp], xa, acc1[b]);
                    acc1[b + 4] = fdot2_(w1[jp], xb, acc1[b + 4]);
                }
            }
        }

        // reduce-scatter over the 4 jq lanes (xor 1 then xor 2, cndmask selects)
        const bool lo1 = (jq & 1) == 0;
        const bool lo2 = (jq & 2) == 0;
        float n0[4], n1[4];
        #pragma unroll
        for (int k = 0; k < 4; ++k) {
            float mine   = lo1 ? acc0[k] : acc0[k + 4];
            float theirs = lo1 ? acc0[k + 4] : acc0[k];
            n0[k] = mine + __shfl_xor(theirs, 1, 64);
            float mine1   = lo1 ? acc1[k] : acc1[k + 4];
            float theirs1 = lo1 ? acc1[k + 4] : acc1[k];
            n1[k] = mine1 + __shfl_xor(theirs1, 1, 64);
        }
        #pragma unroll
        for (int k = 0; k < 2; ++k) {
            float mine   = lo2 ? n0[k] : n0[k + 2];
            float theirs = lo2 ? n0[k + 2] : n0[k];
            float r0 = mine + __shfl_xor(theirs, 2, 64);
            float mine1   = lo2 ? n1[k] : n1[k + 2];
            float theirs1 = lo2 ? n1[k + 2] : n1[k];
            float r1 = mine1 + __shfl_xor(theirs1, 2, 64);
            st[k][sl]     = (_Float16)r0;                 // (i0, b = bsel+k)
            st[2 + k][sl] = (_Float16)r1;                 // (i1, b = bsel+k)
        }
    }

    // stores: 4 x h8 (16B, s-contiguous)
    #pragma unroll
    for (int k = 0; k < 2; ++k) {
        *(h8*)&NT[((size_t)(bsel + k) * DD + il) * S_INN + s0]        = st[k];
        *(h8*)&NT[((size_t)(bsel + k) * DD + il + 64) * S_INN + s0]   = st[2 + k];
    }
}

// ---------------------------------------------------------------------------
// kXf: transpose+convert f32 (R x C) -> f16 (C x R), 64x64 LDS tiles.
// ---------------------------------------------------------------------------
__global__ __launch_bounds__(256) void kXf(const float* __restrict__ src,
                                           _Float16* __restrict__ dst,
                                           int R, int C) {
    const size_t sb = (size_t)blockIdx.z * (size_t)R * C;
    const int r0 = blockIdx.x * 64, c0 = blockIdx.y * 64;
    __shared__ float tile[64][67];
    const int tid = threadIdx.x;
    {
        const int lr = tid >> 2, lc = (tid & 3) * 16;
        const float4* srow = (const float4*)&src[sb + (size_t)(r0 + lr) * C + c0 + lc];
        float4 v0 = srow[0], v1 = srow[1], v2 = srow[2], v3 = srow[3];
        *(float4*)&tile[lr][lc +  0] = v0;
        *(float4*)&tile[lr][lc +  4] = v1;
        *(float4*)&tile[lr][lc +  8] = v2;
        *(float4*)&tile[lr][lc + 12] = v3;
    }
    __syncthreads();
    {
        const int wc = tid >> 2, wsx = (tid & 3) * 16;
        h8 o0, o1;
        #pragma unroll
        for (int k = 0; k < 8; ++k) o0[k] = (_Float16)tile[wsx + k][wc];
        #pragma unroll
        for (int k = 0; k < 8; ++k) o1[k] = (_Float16)tile[wsx + 8 + k][wc];
        _Float16* drow = &dst[sb + (size_t)(c0 + wc) * R + r0 + wsx];
        *(h8*)&drow[0] = o0;
        *(h8*)&drow[8] = o1;
    }
}

// ---------------------------------------------------------------------------
// Kernel C (MFMA, LDS double-buffered): one GEMM  C[t, b*128+i] over K=s.
// Grid (64, 4); 512 thr = 8 waves (2m x 4n); wave tile 64t x 32n; BK=64.
// LDS 64KB: 2 bufs x (A+B 128x64 f16), XOR-swizzled via pre-swizzled source.
// ---------------------------------------------------------------------------
__global__ __launch_bounds__(512) void kC(const _Float16* __restrict__ NT,
                                          const _Float16* __restrict__ LT,
                                          float* __restrict__ part) {
    __shared__ _Float16 lds_pool[4 * 8192];   // [buf][A|B][128*64]

    const int tid  = threadIdx.x;
    const int lane = tid & 63;
    const int w    = tid >> 6;
    const int wm   = w >> 2;
    const int wn   = w & 3;
    const int lr   = lane & 15;
    const int lh   = lane >> 4;

    const int mt = blockIdx.x >> 3;
    const int nt = blockIdx.x & 7;    // = b
    const int kz = blockIdx.y;
    const int t0 = mt * 128;
    const int n0 = nt * 128;
    const int sbase = kz * 1024;

    const int swz = (lr & 7) << 4;

    f32x4 acc[4][2];
    #pragma unroll
    for (int m = 0; m < 4; ++m)
        #pragma unroll
        for (int n = 0; n < 2; ++n) acc[m][n] = (f32x4){0.f, 0.f, 0.f, 0.f};

    auto stage = [&](int buf, int s0) {
        _Float16* base = &lds_pool[buf * 16384];
        #pragma unroll
        for (int ro = 0; ro < 2; ++ro) {
            int idx = tid + ro * 512;
            int r   = idx >> 3;
            int kb  = idx & 7;
            int skb = kb ^ (r & 7);
            gload16(&LT[(size_t)(t0 + r) * S_INN + s0 + skb * 8], base + idx * 8);
            gload16(&NT[(size_t)(n0 + r) * S_INN + s0 + skb * 8], base + 8192 + idx * 8);
        }
    };

    auto compute = [&](int buf) {
        const char* ldsA = (const char*)&lds_pool[buf * 16384];
        const char* ldsB = ldsA + 16384;
        #pragma unroll
        for (int kk = 0; kk < 2; ++kk) {
            const int kb = (kk * 64 + lh * 16) ^ swz;
            h8 a[4], bf[2];
            #pragma unroll
            for (int m = 0; m < 4; ++m)
                a[m] = *(const h8*)(ldsA + (wm * 64 + m * 16 + lr) * 128 + kb);
            #pragma unroll
            for (int n = 0; n < 2; ++n)
                bf[n] = *(const h8*)(ldsB + (wn * 32 + n * 16 + lr) * 128 + kb);
            #pragma unroll
            for (int m = 0; m < 4; ++m)
                #pragma unroll
                for (int n = 0; n < 2; ++n)
                    acc[m][n] = __builtin_amdgcn_mfma_f32_16x16x32_f16(a[m], bf[n], acc[m][n], 0, 0, 0);
        }
    };

    stage(0, sbase);
    __syncthreads();
    for (int st = 0; st < 16; ++st) {
        const int cur = st & 1;
        if (st < 15) stage(cur ^ 1, sbase + (st + 1) * 64);
        compute(cur);
        __syncthreads();
    }

    float* dst = &part[(size_t)(kz * B_SZ + nt) * S_OUTT * DD];
    #pragma unroll
    for (int m = 0; m < 4; ++m) {
        const int t = t0 + wm * 64 + m * 16 + lh * 4;
        #pragma unroll
        for (int n = 0; n < 2; ++n) {
            const int i = wn * 32 + n * 16 + lr;
            #pragma unroll
            for (int r = 0; r < 4; ++r)
                dst[(size_t)(t + r) * DD + i] = acc[m][n][r];
        }
    }
}

// ---------------------------------------------------------------------------
// Kernel D: out = sum of the 4 K-split partials
// ---------------------------------------------------------------------------
__global__ __launch_bounds__(256) void kD(const float* __restrict__ part,
                                          float* __restrict__ out) {
    const int e4 = blockIdx.x * 256 + threadIdx.x;
    const float4* p = (const float4*)part;
    float4 a  = p[e4];
    float4 b1 = p[e4 + 262144];
    float4 c1 = p[e4 + 2 * 262144];
    float4 d1 = p[e4 + 3 * 262144];
    float4 o;
    o.x = a.x + b1.x + c1.x + d1.x;
    o.y = a.y + b1.y + c1.y + d1.y;
    o.z = a.z + b1.z + c1.z + d1.z;
    o.w = a.w + b1.w + c1.w + d1.w;
    ((float4*)out)[e4] = o;
}

extern "C" void kernel_launch(void* const* d_in, const int* in_sizes, int n_in,
                              void* d_out, int out_size, void* d_ws, size_t ws_size,
                              hipStream_t stream) {
    const float* x     = (const float*)d_in[0];
    const float* M     = (const float*)d_in[1];
    const float* P     = (const float*)d_in[2];
    const float* Lk    = (const float*)d_in[3];
    const float* gamma = (const float*)d_in[4];
    const float* beta  = (const float*)d_in[5];
    float* out = (float*)d_out;

    float* wsf = (float*)d_ws;
    _Float16*  xn16 = (_Float16*)(wsf + XN_OFF);    // f16 (B,S,D), dead after kB
    _Float16*  NT   = (_Float16*)(wsf + NT_OFF);    // f16 (B,D,S), written by kB
    _Float16*  LT   = (_Float16*)(wsf + LT_OFF);    // f16 (T,S)
    float*     part = wsf + XN_OFF;                 // reuse xn region

    hipLaunchKernelGGL(kA,  dim3(512),        dim3(256), 0, stream, x, M, gamma, beta, xn16);
    hipLaunchKernelGGL(kB,  dim3(512),        dim3(256), 0, stream, xn16, P, NT);
    hipLaunchKernelGGL(kXf, dim3(64, 16, 1),  dim3(256), 0, stream, Lk, LT, S_INN, S_OUTT);
    hipLaunchKernelGGL(kC,  dim3(64, 4),      dim3(512), 0, stream, NT, LT, part);
    hipLaunchKernelGGL(kD,  dim3(1024),       dim3(256), 0, stream, part, out);
}

// Round 9
// 162.211 us; speedup vs baseline: 1.4740x; 1.0419x over previous
//
#include <hip/hip_runtime.h>
#include <math.h>

#define B_SZ   8
#define S_INN  4096
#define S_OUTT 1024
#define DD     128
#define EPS_LN 1e-5f

typedef _Float16 h2 __attribute__((ext_vector_type(2)));
typedef _Float16 h4 __attribute__((ext_vector_type(4)));
typedef _Float16 h8 __attribute__((ext_vector_type(8)));
typedef float f32x4 __attribute__((ext_vector_type(4)));

// ws layout (float offsets):
//   xn16  [0, ...)              f16  (B,S,D)   dead after kB -> region reused by part (16MB)
//   NT    [6291456,  8388608)   f16  (B,D,S)   (= GEMM B-matrix [b*128+i][s]) written by kB
//   LT    [8388608, 10485760)   f16  (T,S)     = Linker transposed
#define XN_OFF   0
#define NT_OFF   6291456
#define LT_OFF   8388608

__device__ __forceinline__ void gload16(const void* g, void* l) {
    __builtin_amdgcn_global_load_lds(
        (const __attribute__((address_space(1))) unsigned int*)g,
        (__attribute__((address_space(3))) unsigned int*)l, 16, 0, 0);
}

__device__ __forceinline__ float fdot2_(h2 a, h2 b, float c) {
#if __has_builtin(__builtin_amdgcn_fdot2)
    return __builtin_amdgcn_fdot2(a, b, c, false);
#else
    return fmaf((float)a[0], (float)b[0], fmaf((float)a[1], (float)b[1], c));
#endif
}

__device__ __forceinline__ float fract_(float x) {
#if __has_builtin(__builtin_amdgcn_fractf)
    return __builtin_amdgcn_fractf(x);
#else
    return x - floorf(x);
#endif
}

// ---------------------------------------------------------------------------
// Kernel A: xn16 = (f16) [ LayerNorm(x @ M^T) * gamma + beta ]
// 512 blocks x 256 thr; 64 rows/block; thread computes 2 rows x 16 cols.
// ---------------------------------------------------------------------------
__global__ __launch_bounds__(256) void kA(const float* __restrict__ x,
                                          const float* __restrict__ M,
                                          const float* __restrict__ gamma,
                                          const float* __restrict__ beta,
                                          _Float16* __restrict__ xn16) {
    __shared__ float Ms[128 * 128];

    const int tid = threadIdx.x;
    #pragma unroll
    for (int k = 0; k < 16; ++k) {
        int e4 = tid + k * 256;
        int i  = e4 >> 5;
        int j4 = e4 & 31;
        float4 v = *(const float4*)&M[i * DD + j4 * 4];
        int igp = (i >> 4) & 7;
        int qp  = (i >> 2) & 3;
        int cp  = i & 3;
        int col = (qp * 8 + igp) * 4 + cp;
        Ms[(j4 * 4 + 0) * 128 + col] = v.x;
        Ms[(j4 * 4 + 1) * 128 + col] = v.y;
        Ms[(j4 * 4 + 2) * 128 + col] = v.z;
        Ms[(j4 * 4 + 3) * 128 + col] = v.w;
    }
    __syncthreads();

    const int ig = tid & 7;
    const int rg = tid >> 3;
    const int row0 = blockIdx.x * 64 + rg * 2;

    float acc[2][16];
    #pragma unroll
    for (int rr = 0; rr < 2; ++rr)
        #pragma unroll
        for (int k = 0; k < 16; ++k) acc[rr][k] = 0.f;

    const float4* xr[2];
    #pragma unroll
    for (int rr = 0; rr < 2; ++rr) xr[rr] = (const float4*)&x[(size_t)(row0 + rr) * DD];

    for (int j4 = 0; j4 < 32; ++j4) {
        float xvf[2][4];
        #pragma unroll
        for (int rr = 0; rr < 2; ++rr) {
            float4 t = xr[rr][j4];
            xvf[rr][0] = t.x; xvf[rr][1] = t.y; xvf[rr][2] = t.z; xvf[rr][3] = t.w;
        }
        #pragma unroll
        for (int c = 0; c < 4; ++c) {
            const float* Mrow = &Ms[(j4 * 4 + c) * 128];
            #pragma unroll
            for (int q = 0; q < 4; ++q) {
                const float4 mv = *(const float4*)&Mrow[(q * 8 + ig) * 4];
                #pragma unroll
                for (int rr = 0; rr < 2; ++rr) {
                    acc[rr][q * 4 + 0] = fmaf(xvf[rr][c], mv.x, acc[rr][q * 4 + 0]);
                    acc[rr][q * 4 + 1] = fmaf(xvf[rr][c], mv.y, acc[rr][q * 4 + 1]);
                    acc[rr][q * 4 + 2] = fmaf(xvf[rr][c], mv.z, acc[rr][q * 4 + 2]);
                    acc[rr][q * 4 + 3] = fmaf(xvf[rr][c], mv.w, acc[rr][q * 4 + 3]);
                }
            }
        }
    }

    float g[16], be[16];
    #pragma unroll
    for (int q = 0; q < 4; ++q) {
        float4 gv = *(const float4*)&gamma[ig * 16 + q * 4];
        float4 bv = *(const float4*)&beta[ig * 16 + q * 4];
        g[q*4+0]=gv.x; g[q*4+1]=gv.y; g[q*4+2]=gv.z; g[q*4+3]=gv.w;
        be[q*4+0]=bv.x; be[q*4+1]=bv.y; be[q*4+2]=bv.z; be[q*4+3]=bv.w;
    }
    #pragma unroll
    for (int rr = 0; rr < 2; ++rr) {
        float s1 = 0.f, s2 = 0.f;
        #pragma unroll
        for (int k = 0; k < 16; ++k) { s1 += acc[rr][k]; s2 = fmaf(acc[rr][k], acc[rr][k], s2); }
        #pragma unroll
        for (int m = 1; m < 8; m <<= 1) {
            s1 += __shfl_xor(s1, m, 64);
            s2 += __shfl_xor(s2, m, 64);
        }
        float mu  = s1 * (1.f / 128.f);
        float var = s2 * (1.f / 128.f) - mu * mu;
        float rstd = rsqrtf(var + EPS_LN);
        _Float16* dst = &xn16[(size_t)(row0 + rr) * DD + ig * 16];
        #pragma unroll
        for (int q = 0; q < 4; ++q) {
            h4 hv;
            hv[0] = (_Float16)((acc[rr][q*4+0] - mu) * rstd * g[q*4+0] + be[q*4+0]);
            hv[1] = (_Float16)((acc[rr][q*4+1] - mu) * rstd * g[q*4+1] + be[q*4+1]);
            hv[2] = (_Float16)((acc[rr][q*4+2] - mu) * rstd * g[q*4+2] + be[q*4+2]);
            hv[3] = (_Float16)((acc[rr][q*4+3] - mu) * rstd * g[q*4+3] + be[q*4+3]);
            *(h4*)&dst[q * 4] = hv;
        }
    }
}

// ---------------------------------------------------------------------------
// Kernel B (s-tiled, hoisted rcp): NT[b*128+i][s] =
//   (f16) sum_j xn[b,s,j]*P[i,j]*cos_rev(s/(i*128+j+2))
// grid 512 (8 s each) x 256 thr; thread = (il=tid>>2, jq=tid&3): i in {il,il+64},
// j in [jq*32,+32). Phase 0 computes all 64 rcp(p) ONCE (only loop-invariant
// trans); per phi the cost is then 1 v_cos + mul/fract (full-rate VALU).
// Numerically identical to the unhoisted form. Reduce-scatter + direct h8
// NT stores as before.
// ---------------------------------------------------------------------------
__global__ __launch_bounds__(256) void kB(const _Float16* __restrict__ xn16,
                                          const float* __restrict__ P,
                                          _Float16* __restrict__ NT) {
    const int s0 = blockIdx.x * 8;
    __shared__ _Float16 Ps[128 * 136];     // 34.8 KB
    __shared__ _Float16 xs[8 * 1024];      // 16 KB: [s][slot(j2)][b][2]

    const int tid = threadIdx.x;
    // stage xs: 1024 chunks of 8 f16
    #pragma unroll
    for (int k = 0; k < 4; ++k) {
        int c   = tid + k * 256;
        int row = c >> 4;                  // b = row>>3, sl = row&7
        int b   = row >> 3, sl = row & 7;
        int kk  = c & 15;                  // j = kk*8
        h8 v = *(const h8*)&xn16[((size_t)b * S_INN + s0 + sl) * DD + kk * 8];
        #pragma unroll
        for (int q = 0; q < 4; ++q) {
            int j2 = kk * 4 + q;
            int slot = (j2 & 15) * 4 + (j2 >> 4);
            *(h2*)&xs[sl * 1024 + slot * 16 + b * 2] = h2{ v[q * 2], v[q * 2 + 1] };
        }
    }
    // stage Ps (f32 -> f16)
    #pragma unroll
    for (int k = 0; k < 16; ++k) {
        int e4 = tid + k * 256;
        int ip = e4 >> 5, j4 = e4 & 31;
        float4 v = *(const float4*)&P[ip * DD + j4 * 4];
        *(h4*)&Ps[ip * 136 + j4 * 4] = h4{ (_Float16)v.x, (_Float16)v.y,
                                           (_Float16)v.z, (_Float16)v.w };
    }
    __syncthreads();

    const int il = tid >> 2;
    const int jq = tid & 3;
    const int j0base = jq * 32;
    const float s0f = (float)s0;
    const float pb0 = (float)(il * DD + j0base + 2);      // p base, i = il
    const int bsel = ((jq & 1) << 2) | (jq & 2);          // owned b-pair base

    // Phase 0: hoist ALL rcp(p) out of the s-loop (loop-invariant trans).
    float invp0[32], invp1[32];
    #pragma unroll
    for (int jj = 0; jj < 32; ++jj) {
        float pf0 = pb0 + (float)jj;
        invp0[jj] = __builtin_amdgcn_rcpf(pf0);
        invp1[jj] = __builtin_amdgcn_rcpf(pf0 + 8192.f);  // (il+64)*128
    }

    h8 st[4];                                             // [ih*2+k] packs 8 s
    #pragma unroll
    for (int s_ = 0; s_ < 4; ++s_) st[s_] = h8{};

    #pragma unroll
    for (int sl = 0; sl < 8; ++sl) {
        const float sf = s0f + (float)sl;
        float acc0[8] = {0,0,0,0,0,0,0,0};
        float acc1[8] = {0,0,0,0,0,0,0,0};

        #pragma unroll
        for (int j8 = 0; j8 < 4; ++j8) {
            h8 p0 = *(const h8*)&Ps[il * 136 + j0base + j8 * 8];
            h8 p1 = *(const h8*)&Ps[(il + 64) * 136 + j0base + j8 * 8];

            h2 w0[4], w1[4];
            #pragma unroll
            for (int cp = 0; cp < 4; ++cp) {
                float wv0[2], wv1[2];
                #pragma unroll
                for (int u = 0; u < 2; ++u) {
                    int c = cp * 2 + u;
                    int jj = j8 * 8 + c;
                    float r0 = fract_(sf * invp0[jj]);
                    wv0[u] = (float)p0[c] * __builtin_amdgcn_cosf(r0);
                    float r1 = fract_(sf * invp1[jj]);
                    wv1[u] = (float)p1[c] * __builtin_amdgcn_cosf(r1);
                }
                w0[cp] = h2{ (_Float16)wv0[0], (_Float16)wv0[1] };
                w1[cp] = h2{ (_Float16)wv1[0], (_Float16)wv1[1] };
            }

            #pragma unroll
            for (int jp = 0; jp < 4; ++jp) {
                int slot = (j8 * 4 + jp) * 4 + jq;
                const h8 xlo = *(const h8*)&xs[sl * 1024 + slot * 16];
                const h8 xhi = *(const h8*)&xs[sl * 1024 + slot * 16 + 8];
                #pragma unroll
                for (int b = 0; b < 4; ++b) {
                    h2 xa = h2{ xlo[b * 2], xlo[b * 2 + 1] };
                    h2 xb = h2{ xhi[b * 2], xhi[b * 2 + 1] };
                    acc0[b]     = fdot2_(w0[jp], xa, acc0[b]);
                    acc0[b + 4] = fdot2_(w0[jp], xb, acc0[b + 4]);
                    acc1[b]     = fdot2_(w1[jp], xa, acc1[b]);
                    acc1[b + 4] = fdot2_(w1[jp], xb, acc1[b + 4]);
                }
            }
        }

        // reduce-scatter over the 4 jq lanes (xor 1 then xor 2, cndmask selects)
        const bool lo1 = (jq & 1) == 0;
        const bool lo2 = (jq & 2) == 0;
        float n0[4], n1[4];
        #pragma unroll
        for (int k = 0; k < 4; ++k) {
            float mine   = lo1 ? acc0[k] : acc0[k + 4];
            float theirs = lo1 ? acc0[k + 4] : acc0[k];
            n0[k] = mine + __shfl_xor(theirs, 1, 64);
            float mine1   = lo1 ? acc1[k] : acc1[k + 4];
            float theirs1 = lo1 ? acc1[k + 4] : acc1[k];
            n1[k] = mine1 + __shfl_xor(theirs1, 1, 64);
        }
        #pragma unroll
        for (int k = 0; k < 2; ++k) {
            float mine   = lo2 ? n0[k] : n0[k + 2];
            float theirs = lo2 ? n0[k + 2] : n0[k];
            float r0 = mine + __shfl_xor(theirs, 2, 64);
            float mine1   = lo2 ? n1[k] : n1[k + 2];
            float theirs1 = lo2 ? n1[k + 2] : n1[k];
            float r1 = mine1 + __shfl_xor(theirs1, 2, 64);
            st[k][sl]     = (_Float16)r0;                 // (i0, b = bsel+k)
            st[2 + k][sl] = (_Float16)r1;                 // (i1, b = bsel+k)
        }
    }

    // stores: 4 x h8 (16B, s-contiguous)
    #pragma unroll
    for (int k = 0; k < 2; ++k) {
        *(h8*)&NT[((size_t)(bsel + k) * DD + il) * S_INN + s0]        = st[k];
        *(h8*)&NT[((size_t)(bsel + k) * DD + il + 64) * S_INN + s0]   = st[2 + k];
    }
}

// ---------------------------------------------------------------------------
// kXf: transpose+convert f32 (R x C) -> f16 (C x R), 64x64 LDS tiles.
// ---------------------------------------------------------------------------
__global__ __launch_bounds__(256) void kXf(const float* __restrict__ src,
                                           _Float16* __restrict__ dst,
                                           int R, int C) {
    const size_t sb = (size_t)blockIdx.z * (size_t)R * C;
    const int r0 = blockIdx.x * 64, c0 = blockIdx.y * 64;
    __shared__ float tile[64][67];
    const int tid = threadIdx.x;
    {
        const int lr = tid >> 2, lc = (tid & 3) * 16;
        const float4* srow = (const float4*)&src[sb + (size_t)(r0 + lr) * C + c0 + lc];
        float4 v0 = srow[0], v1 = srow[1], v2 = srow[2], v3 = srow[3];
        *(float4*)&tile[lr][lc +  0] = v0;
        *(float4*)&tile[lr][lc +  4] = v1;
        *(float4*)&tile[lr][lc +  8] = v2;
        *(float4*)&tile[lr][lc + 12] = v3;
    }
    __syncthreads();
    {
        const int wc = tid >> 2, wsx = (tid & 3) * 16;
        h8 o0, o1;
        #pragma unroll
        for (int k = 0; k < 8; ++k) o0[k] = (_Float16)tile[wsx + k][wc];
        #pragma unroll
        for (int k = 0; k < 8; ++k) o1[k] = (_Float16)tile[wsx + 8 + k][wc];
        _Float16* drow = &dst[sb + (size_t)(c0 + wc) * R + r0 + wsx];
        *(h8*)&drow[0] = o0;
        *(h8*)&drow[8] = o1;
    }
}

// ---------------------------------------------------------------------------
// Kernel C (MFMA, LDS double-buffered): one GEMM  C[t, b*128+i] over K=s.
// Grid (64, 4); 512 thr = 8 waves (2m x 4n); wave tile 64t x 32n; BK=64.
// LDS 64KB: 2 bufs x (A+B 128x64 f16), XOR-swizzled via pre-swizzled source.
// ---------------------------------------------------------------------------
__global__ __launch_bounds__(512) void kC(const _Float16* __restrict__ NT,
                                          const _Float16* __restrict__ LT,
                                          float* __restrict__ part) {
    __shared__ _Float16 lds_pool[4 * 8192];   // [buf][A|B][128*64]

    const int tid  = threadIdx.x;
    const int lane = tid & 63;
    const int w    = tid >> 6;
    const int wm   = w >> 2;
    const int wn   = w & 3;
    const int lr   = lane & 15;
    const int lh   = lane >> 4;

    const int mt = blockIdx.x >> 3;
    const int nt = blockIdx.x & 7;    // = b
    const int kz = blockIdx.y;
    const int t0 = mt * 128;
    const int n0 = nt * 128;
    const int sbase = kz * 1024;

    const int swz = (lr & 7) << 4;

    f32x4 acc[4][2];
    #pragma unroll
    for (int m = 0; m < 4; ++m)
        #pragma unroll
        for (int n = 0; n < 2; ++n) acc[m][n] = (f32x4){0.f, 0.f, 0.f, 0.f};

    auto stage = [&](int buf, int s0) {
        _Float16* base = &lds_pool[buf * 16384];
        #pragma unroll
        for (int ro = 0; ro < 2; ++ro) {
            int idx = tid + ro * 512;
            int r   = idx >> 3;
            int kb  = idx & 7;
            int skb = kb ^ (r & 7);
            gload16(&LT[(size_t)(t0 + r) * S_INN + s0 + skb * 8], base + idx * 8);
            gload16(&NT[(size_t)(n0 + r) * S_INN + s0 + skb * 8], base + 8192 + idx * 8);
        }
    };

    auto compute = [&](int buf) {
        const char* ldsA = (const char*)&lds_pool[buf * 16384];
        const char* ldsB = ldsA + 16384;
        #pragma unroll
        for (int kk = 0; kk < 2; ++kk) {
            const int kb = (kk * 64 + lh * 16) ^ swz;
            h8 a[4], bf[2];
            #pragma unroll
            for (int m = 0; m < 4; ++m)
                a[m] = *(const h8*)(ldsA + (wm * 64 + m * 16 + lr) * 128 + kb);
            #pragma unroll
            for (int n = 0; n < 2; ++n)
                bf[n] = *(const h8*)(ldsB + (wn * 32 + n * 16 + lr) * 128 + kb);
            #pragma unroll
            for (int m = 0; m < 4; ++m)
                #pragma unroll
                for (int n = 0; n < 2; ++n)
                    acc[m][n] = __builtin_amdgcn_mfma_f32_16x16x32_f16(a[m], bf[n], acc[m][n], 0, 0, 0);
        }
    };

    stage(0, sbase);
    __syncthreads();
    for (int st = 0; st < 16; ++st) {
        const int cur = st & 1;
        if (st < 15) stage(cur ^ 1, sbase + (st + 1) * 64);
        compute(cur);
        __syncthreads();
    }

    float* dst = &part[(size_t)(kz * B_SZ + nt) * S_OUTT * DD];
    #pragma unroll
    for (int m = 0; m < 4; ++m) {
        const int t = t0 + wm * 64 + m * 16 + lh * 4;
        #pragma unroll
        for (int n = 0; n < 2; ++n) {
            const int i = wn * 32 + n * 16 + lr;
            #pragma unroll
            for (int r = 0; r < 4; ++r)
                dst[(size_t)(t + r) * DD + i] = acc[m][n][r];
        }
    }
}

// ---------------------------------------------------------------------------
// Kernel D: out = sum of the 4 K-split partials
// ---------------------------------------------------------------------------
__global__ __launch_bounds__(256) void kD(const float* __restrict__ part,
                                          float* __restrict__ out) {
    const int e4 = blockIdx.x * 256 + threadIdx.x;
    const float4* p = (const float4*)part;
    float4 a  = p[e4];
    float4 b1 = p[e4 + 262144];
    float4 c1 = p[e4 + 2 * 262144];
    float4 d1 = p[e4 + 3 * 262144];
    float4 o;
    o.x = a.x + b1.x + c1.x + d1.x;
    o.y = a.y + b1.y + c1.y + d1.y;
    o.z = a.z + b1.z + c1.z + d1.z;
    o.w = a.w + b1.w + c1.w + d1.w;
    ((float4*)out)[e4] = o;
}

extern "C" void kernel_launch(void* const* d_in, const int* in_sizes, int n_in,
                              void* d_out, int out_size, void* d_ws, size_t ws_size,
                              hipStream_t stream) {
    const float* x     = (const float*)d_in[0];
    const float* M     = (const float*)d_in[1];
    const float* P     = (const float*)d_in[2];
    const float* Lk    = (const float*)d_in[3];
    const float* gamma = (const float*)d_in[4];
    const float* beta  = (const float*)d_in[5];
    float* out = (float*)d_out;

    float* wsf = (float*)d_ws;
    _Float16*  xn16 = (_Float16*)(wsf + XN_OFF);    // f16 (B,S,D), dead after kB
    _Float16*  NT   = (_Float16*)(wsf + NT_OFF);    // f16 (B,D,S), written by kB
    _Float16*  LT   = (_Float16*)(wsf + LT_OFF);    // f16 (T,S)
    float*     part = wsf + XN_OFF;                 // reuse xn region

    hipLaunchKernelGGL(kA,  dim3(512),        dim3(256), 0, stream, x, M, gamma, beta, xn16);
    hipLaunchKernelGGL(kB,  dim3(512),        dim3(256), 0, stream, xn16, P, NT);
    hipLaunchKernelGGL(kXf, dim3(64, 16, 1),  dim3(256), 0, stream, Lk, LT, S_INN, S_OUTT);
    hipLaunchKernelGGL(kC,  dim3(64, 4),      dim3(512), 0, stream, NT, LT, part);
    hipLaunchKernelGGL(kD,  dim3(1024),       dim3(256), 0, stream, part, out);
}

// Round 11
// 142.255 us; speedup vs baseline: 1.6808x; 1.1403x over previous
//
#include <hip/hip_runtime.h>
#include <math.h>

#define B_SZ   8
#define S_INN  4096
#define S_OUTT 1024
#define DD     128
#define EPS_LN 1e-5f

typedef _Float16 h2 __attribute__((ext_vector_type(2)));
typedef _Float16 h4 __attribute__((ext_vector_type(4)));
typedef _Float16 h8 __attribute__((ext_vector_type(8)));
typedef float f32x4 __attribute__((ext_vector_type(4)));

// ws layout (float offsets):
//   xn16  [0, ...)              f16  (B,S,D)   dead after kB -> region reused by part (16MB)
//   NT    [6291456,  8388608)   f16  (B,D,S)   (= GEMM B-matrix [b*128+i][s]) written by kB
//   LT    [8388608, 10485760)   f16  (T,S)     = Linker transposed
#define XN_OFF   0
#define NT_OFF   6291456
#define LT_OFF   8388608

__device__ __forceinline__ void gload16(const void* g, void* l) {
    __builtin_amdgcn_global_load_lds(
        (const __attribute__((address_space(1))) unsigned int*)g,
        (__attribute__((address_space(3))) unsigned int*)l, 16, 0, 0);
}

__device__ __forceinline__ float fdot2_(h2 a, h2 b, float c) {
#if __has_builtin(__builtin_amdgcn_fdot2)
    return __builtin_amdgcn_fdot2(a, b, c, false);
#else
    return fmaf((float)a[0], (float)b[0], fmaf((float)a[1], (float)b[1], c));
#endif
}

__device__ __forceinline__ float fract_(float x) {
#if __has_builtin(__builtin_amdgcn_fractf)
    return __builtin_amdgcn_fractf(x);
#else
    return x - floorf(x);
#endif
}

// ---------------------------------------------------------------------------
// Kernel A (MFMA): xn16 = (f16) [ LayerNorm(x @ M^T) * gamma + beta ]
// 256 blocks x 256 thr (4 waves); block = 128 rows; K=128 in 4 MFMA steps.
// Xs (x-tile) and Msw (all of M) staged once as f16, XOR-swizzled rows
// (chunk ^= row&7) on BOTH write and read. Wave = 32 rows x 128 i, acc[2][8].
// LN epilogue on C-fragments: col=lane&15 (i), row=lh*4+reg; reduce over the
// 8 n-registers + 16-lane shfl_xor tree. Same fragment pattern kC validated.
// ---------------------------------------------------------------------------
__global__ __launch_bounds__(256) void kA(const float* __restrict__ x,
                                          const float* __restrict__ M,
                                          const float* __restrict__ gamma,
                                          const float* __restrict__ beta,
                                          _Float16* __restrict__ xn16) {
    __shared__ _Float16 Xs[128 * 128];    // 32 KB
    __shared__ _Float16 Msw[128 * 128];   // 32 KB

    const int tid  = threadIdx.x;
    const int row0 = blockIdx.x * 128;

    {   // stage: thread = (rw = tid>>1, hf = tid&1): one row-half of x AND of M
        const int rw = tid >> 1, hf = tid & 1;
        const float4* xsrc = (const float4*)&x[(size_t)(row0 + rw) * DD + hf * 64];
        const float4* msrc = (const float4*)&M[rw * DD + hf * 64];
        #pragma unroll
        for (int q = 0; q < 8; ++q) {               // 8 x 16B chunks per half-row
            float4 v0 = xsrc[q * 2], v1 = xsrc[q * 2 + 1];
            h8 hx = { (_Float16)v0.x, (_Float16)v0.y, (_Float16)v0.z, (_Float16)v0.w,
                      (_Float16)v1.x, (_Float16)v1.y, (_Float16)v1.z, (_Float16)v1.w };
            float4 m0 = msrc[q * 2], m1 = msrc[q * 2 + 1];
            h8 hm = { (_Float16)m0.x, (_Float16)m0.y, (_Float16)m0.z, (_Float16)m0.w,
                      (_Float16)m1.x, (_Float16)m1.y, (_Float16)m1.z, (_Float16)m1.w };
            int c  = hf * 8 + q;                    // global chunk 0..15
            int cs = c ^ (rw & 7);                  // swizzled chunk
            *(h8*)&Xs[rw * 128 + cs * 8]  = hx;
            *(h8*)&Msw[rw * 128 + cs * 8] = hm;
        }
    }
    __syncthreads();

    const int lane = tid & 63, w = tid >> 6;
    const int lr = lane & 15, lh = lane >> 4;
    const int rw0 = w * 32;

    f32x4 acc[2][8];
    #pragma unroll
    for (int m = 0; m < 2; ++m)
        #pragma unroll
        for (int n = 0; n < 8; ++n) acc[m][n] = (f32x4){0.f, 0.f, 0.f, 0.f};

    #pragma unroll
    for (int ks = 0; ks < 4; ++ks) {
        h8 a[2], bb[8];
        #pragma unroll
        for (int m = 0; m < 2; ++m) {
            int row = rw0 + m * 16 + lr;
            int cj  = (ks * 4 + lh) ^ (row & 7);
            a[m] = *(const h8*)&Xs[row * 128 + cj * 8];
        }
        #pragma unroll
        for (int n = 0; n < 8; ++n) {
            int irow = n * 16 + lr;
            int cj   = (ks * 4 + lh) ^ (irow & 7);
            bb[n] = *(const h8*)&Msw[irow * 128 + cj * 8];
        }
        #pragma unroll
        for (int m = 0; m < 2; ++m)
            #pragma unroll
            for (int n = 0; n < 8; ++n)
                acc[m][n] = __builtin_amdgcn_mfma_f32_16x16x32_f16(a[m], bb[n], acc[m][n], 0, 0, 0);
    }

    float g[8], be[8];
    #pragma unroll
    for (int n = 0; n < 8; ++n) { g[n] = gamma[n * 16 + lr]; be[n] = beta[n * 16 + lr]; }

    #pragma unroll
    for (int m = 0; m < 2; ++m) {
        #pragma unroll
        for (int r = 0; r < 4; ++r) {
            float s1 = 0.f, s2 = 0.f;
            #pragma unroll
            for (int n = 0; n < 8; ++n) { float v = acc[m][n][r]; s1 += v; s2 = fmaf(v, v, s2); }
            #pragma unroll
            for (int mm = 1; mm < 16; mm <<= 1) {
                s1 += __shfl_xor(s1, mm, 64);
                s2 += __shfl_xor(s2, mm, 64);
            }
            float mu   = s1 * (1.f / 128.f);
            float var  = s2 * (1.f / 128.f) - mu * mu;
            float rstd = rsqrtf(var + EPS_LN);
            int grow = row0 + rw0 + m * 16 + lh * 4 + r;
            _Float16* dst = &xn16[(size_t)grow * DD];
            #pragma unroll
            for (int n = 0; n < 8; ++n)
                dst[n * 16 + lr] = (_Float16)((acc[m][n][r] - mu) * rstd * g[n] + be[n]);
        }
    }
}

// ---------------------------------------------------------------------------
// Kernel B (s-tiled, hoisted rcp + hoisted P-regs): NT[b*128+i][s] =
//   (f16) sum_j xn[b,s,j]*P[i,j]*cos_rev(s/(i*128+j+2))
// grid 512 (8 s each) x 256 thr; thread = (il=tid>>2, jq=tid&3): i in {il,il+64},
// j in [jq*32,+32). rcp(p) and the 8 P-fragment reads hoisted out of the
// s-loop into registers (explicitly, not relying on LICM).
// ---------------------------------------------------------------------------
__global__ __launch_bounds__(256) void kB(const _Float16* __restrict__ xn16,
                                          const float* __restrict__ P,
                                          _Float16* __restrict__ NT) {
    const int s0 = blockIdx.x * 8;
    __shared__ _Float16 Ps[128 * 136];     // 34.8 KB
    __shared__ _Float16 xs[8 * 1024];      // 16 KB: [s][slot(j2)][b][2]

    const int tid = threadIdx.x;
    // stage xs: 1024 chunks of 8 f16
    #pragma unroll
    for (int k = 0; k < 4; ++k) {
        int c   = tid + k * 256;
        int row = c >> 4;                  // b = row>>3, sl = row&7
        int b   = row >> 3, sl = row & 7;
        int kk  = c & 15;                  // j = kk*8
        h8 v = *(const h8*)&xn16[((size_t)b * S_INN + s0 + sl) * DD + kk * 8];
        #pragma unroll
        for (int q = 0; q < 4; ++q) {
            int j2 = kk * 4 + q;
            int slot = (j2 & 15) * 4 + (j2 >> 4);
            *(h2*)&xs[sl * 1024 + slot * 16 + b * 2] = h2{ v[q * 2], v[q * 2 + 1] };
        }
    }
    // stage Ps (f32 -> f16)
    #pragma unroll
    for (int k = 0; k < 16; ++k) {
        int e4 = tid + k * 256;
        int ip = e4 >> 5, j4 = e4 & 31;
        float4 v = *(const float4*)&P[ip * DD + j4 * 4];
        *(h4*)&Ps[ip * 136 + j4 * 4] = h4{ (_Float16)v.x, (_Float16)v.y,
                                           (_Float16)v.z, (_Float16)v.w };
    }
    __syncthreads();

    const int il = tid >> 2;
    const int jq = tid & 3;
    const int j0base = jq * 32;
    const float s0f = (float)s0;
    const float pb0 = (float)(il * DD + j0base + 2);      // p base, i = il
    const int bsel = ((jq & 1) << 2) | (jq & 2);          // owned b-pair base

    // Hoist ALL rcp(p) (loop-invariant trans) and all P fragments into regs.
    float invp0[32], invp1[32];
    #pragma unroll
    for (int jj = 0; jj < 32; ++jj) {
        float pf0 = pb0 + (float)jj;
        invp0[jj] = __builtin_amdgcn_rcpf(pf0);
        invp1[jj] = __builtin_amdgcn_rcpf(pf0 + 8192.f);  // (il+64)*128
    }
    h8 p0r[4], p1r[4];
    #pragma unroll
    for (int j8 = 0; j8 < 4; ++j8) {
        p0r[j8] = *(const h8*)&Ps[il * 136 + j0base + j8 * 8];
        p1r[j8] = *(const h8*)&Ps[(il + 64) * 136 + j0base + j8 * 8];
    }

    h8 st[4];                                             // [ih*2+k] packs 8 s
    #pragma unroll
    for (int s_ = 0; s_ < 4; ++s_) st[s_] = h8{};

    #pragma unroll
    for (int sl = 0; sl < 8; ++sl) {
        const float sf = s0f + (float)sl;
        float acc0[8] = {0,0,0,0,0,0,0,0};
        float acc1[8] = {0,0,0,0,0,0,0,0};

        #pragma unroll
        for (int j8 = 0; j8 < 4; ++j8) {
            h2 w0[4], w1[4];
            #pragma unroll
            for (int cp = 0; cp < 4; ++cp) {
                float wv0[2], wv1[2];
                #pragma unroll
                for (int u = 0; u < 2; ++u) {
                    int c = cp * 2 + u;
                    int jj = j8 * 8 + c;
                    float r0 = fract_(sf * invp0[jj]);
                    wv0[u] = (float)p0r[j8][c] * __builtin_amdgcn_cosf(r0);
                    float r1 = fract_(sf * invp1[jj]);
                    wv1[u] = (float)p1r[j8][c] * __builtin_amdgcn_cosf(r1);
                }
                w0[cp] = h2{ (_Float16)wv0[0], (_Float16)wv0[1] };
                w1[cp] = h2{ (_Float16)wv1[0], (_Float16)wv1[1] };
            }

            #pragma unroll
            for (int jp = 0; jp < 4; ++jp) {
                int slot = (j8 * 4 + jp) * 4 + jq;
                const h8 xlo = *(const h8*)&xs[sl * 1024 + slot * 16];
                const h8 xhi = *(const h8*)&xs[sl * 1024 + slot * 16 + 8];
                #pragma unroll
                for (int b = 0; b < 4; ++b) {
                    h2 xa = h2{ xlo[b * 2], xlo[b * 2 + 1] };
                    h2 xb = h2{ xhi[b * 2], xhi[b * 2 + 1] };
                    acc0[b]     = fdot2_(w0[jp], xa, acc0[b]);
                    acc0[b + 4] = fdot2_(w0[jp], xb, acc0[b + 4]);
                    acc1[b]     = fdot2_(w1[jp], xa, acc1[b]);
                    acc1[b + 4] = fdot2_(w1[jp], xb, acc1[b + 4]);
                }
            }
        }

        // reduce-scatter over the 4 jq lanes (xor 1 then xor 2, cndmask selects)
        const bool lo1 = (jq & 1) == 0;
        const bool lo2 = (jq & 2) == 0;
        float n0[4], n1[4];
        #pragma unroll
        for (int k = 0; k < 4; ++k) {
            float mine   = lo1 ? acc0[k] : acc0[k + 4];
            float theirs = lo1 ? acc0[k + 4] : acc0[k];
            n0[k] = mine + __shfl_xor(theirs, 1, 64);
            float mine1   = lo1 ? acc1[k] : acc1[k + 4];
            float theirs1 = lo1 ? acc1[k + 4] : acc1[k];
            n1[k] = mine1 + __shfl_xor(theirs1, 1, 64);
        }
        #pragma unroll
        for (int k = 0; k < 2; ++k) {
            float mine   = lo2 ? n0[k] : n0[k + 2];
            float theirs = lo2 ? n0[k + 2] : n0[k];
            float r0 = mine + __shfl_xor(theirs, 2, 64);
            float mine1   = lo2 ? n1[k] : n1[k + 2];
            float theirs1 = lo2 ? n1[k + 2] : n1[k];
            float r1 = mine1 + __shfl_xor(theirs1, 2, 64);
            st[k][sl]     = (_Float16)r0;                 // (i0, b = bsel+k)
            st[2 + k][sl] = (_Float16)r1;                 // (i1, b = bsel+k)
        }
    }

    // stores: 4 x h8 (16B, s-contiguous)
    #pragma unroll
    for (int k = 0; k < 2; ++k) {
        *(h8*)&NT[((size_t)(bsel + k) * DD + il) * S_INN + s0]        = st[k];
        *(h8*)&NT[((size_t)(bsel + k) * DD + il + 64) * S_INN + s0]   = st[2 + k];
    }
}

// ---------------------------------------------------------------------------
// kXf: transpose+convert f32 (R x C) -> f16 (C x R), 64x64 LDS tiles.
// ---------------------------------------------------------------------------
__global__ __launch_bounds__(256) void kXf(const float* __restrict__ src,
                                           _Float16* __restrict__ dst,
                                           int R, int C) {
    const size_t sb = (size_t)blockIdx.z * (size_t)R * C;
    const int r0 = blockIdx.x * 64, c0 = blockIdx.y * 64;
    __shared__ float tile[64][67];
    const int tid = threadIdx.x;
    {
        const int lr = tid >> 2, lc = (tid & 3) * 16;
        const float4* srow = (const float4*)&src[sb + (size_t)(r0 + lr) * C + c0 + lc];
        float4 v0 = srow[0], v1 = srow[1], v2 = srow[2], v3 = srow[3];
        *(float4*)&tile[lr][lc +  0] = v0;
        *(float4*)&tile[lr][lc +  4] = v1;
        *(float4*)&tile[lr][lc +  8] = v2;
        *(float4*)&tile[lr][lc + 12] = v3;
    }
    __syncthreads();
    {
        const int wc = tid >> 2, wsx = (tid & 3) * 16;
        h8 o0, o1;
        #pragma unroll
        for (int k = 0; k < 8; ++k) o0[k] = (_Float16)tile[wsx + k][wc];
        #pragma unroll
        for (int k = 0; k < 8; ++k) o1[k] = (_Float16)tile[wsx + 8 + k][wc];
        _Float16* drow = &dst[sb + (size_t)(c0 + wc) * R + r0 + wsx];
        *(h8*)&drow[0] = o0;
        *(h8*)&drow[8] = o1;
    }
}

// ---------------------------------------------------------------------------
// Kernel C (MFMA, LDS double-buffered): one GEMM  C[t, b*128+i] over K=s.
// Grid (64, 4); 512 thr = 8 waves (2m x 4n); wave tile 64t x 32n; BK=64.
// LDS 64KB: 2 bufs x (A+B 128x64 f16), XOR-swizzled via pre-swizzled source.
// ---------------------------------------------------------------------------
__global__ __launch_bounds__(512) void kC(const _Float16* __restrict__ NT,
                                          const _Float16* __restrict__ LT,
                                          float* __restrict__ part) {
    __shared__ _Float16 lds_pool[4 * 8192];   // [buf][A|B][128*64]

    const int tid  = threadIdx.x;
    const int lane = tid & 63;
    const int w    = tid >> 6;
    const int wm   = w >> 2;
    const int wn   = w & 3;
    const int lr   = lane & 15;
    const int lh   = lane >> 4;

    const int mt = blockIdx.x >> 3;
    const int nt = blockIdx.x & 7;    // = b
    const int kz = blockIdx.y;
    const int t0 = mt * 128;
    const int n0 = nt * 128;
    const int sbase = kz * 1024;

    const int swz = (lr & 7) << 4;

    f32x4 acc[4][2];
    #pragma unroll
    for (int m = 0; m < 4; ++m)
        #pragma unroll
        for (int n = 0; n < 2; ++n) acc[m][n] = (f32x4){0.f, 0.f, 0.f, 0.f};

    auto stage = [&](int buf, int s0) {
        _Float16* base = &lds_pool[buf * 16384];
        #pragma unroll
        for (int ro = 0; ro < 2; ++ro) {
            int idx = tid + ro * 512;
            int r   = idx >> 3;
            int kb  = idx & 7;
            int skb = kb ^ (r & 7);
            gload16(&LT[(size_t)(t0 + r) * S_INN + s0 + skb * 8], base + idx * 8);
            gload16(&NT[(size_t)(n0 + r) * S_INN + s0 + skb * 8], base + 8192 + idx * 8);
        }
    };

    auto compute = [&](int buf) {
        const char* ldsA = (const char*)&lds_pool[buf * 16384];
        const char* ldsB = ldsA + 16384;
        #pragma unroll
        for (int kk = 0; kk < 2; ++kk) {
            const int kb = (kk * 64 + lh * 16) ^ swz;
            h8 a[4], bf[2];
            #pragma unroll
            for (int m = 0; m < 4; ++m)
                a[m] = *(const h8*)(ldsA + (wm * 64 + m * 16 + lr) * 128 + kb);
            #pragma unroll
            for (int n = 0; n < 2; ++n)
                bf[n] = *(const h8*)(ldsB + (wn * 32 + n * 16 + lr) * 128 + kb);
            #pragma unroll
            for (int m = 0; m < 4; ++m)
                #pragma unroll
                for (int n = 0; n < 2; ++n)
                    acc[m][n] = __builtin_amdgcn_mfma_f32_16x16x32_f16(a[m], bf[n], acc[m][n], 0, 0, 0);
        }
    };

    stage(0, sbase);
    __syncthreads();
    for (int st = 0; st < 16; ++st) {
        const int cur = st & 1;
        if (st < 15) stage(cur ^ 1, sbase + (st + 1) * 64);
        compute(cur);
        __syncthreads();
    }

    float* dst = &part[(size_t)(kz * B_SZ + nt) * S_OUTT * DD];
    #pragma unroll
    for (int m = 0; m < 4; ++m) {
        const int t = t0 + wm * 64 + m * 16 + lh * 4;
        #pragma unroll
        for (int n = 0; n < 2; ++n) {
            const int i = wn * 32 + n * 16 + lr;
            #pragma unroll
            for (int r = 0; r < 4; ++r)
                dst[(size_t)(t + r) * DD + i] = acc[m][n][r];
        }
    }
}

// ---------------------------------------------------------------------------
// Kernel D: out = sum of the 4 K-split partials
// ---------------------------------------------------------------------------
__global__ __launch_bounds__(256) void kD(const float* __restrict__ part,
                                          float* __restrict__ out) {
    const int e4 = blockIdx.x * 256 + threadIdx.x;
    const float4* p = (const float4*)part;
    float4 a  = p[e4];
    float4 b1 = p[e4 + 262144];
    float4 c1 = p[e4 + 2 * 262144];
    float4 d1 = p[e4 + 3 * 262144];
    float4 o;
    o.x = a.x + b1.x + c1.x + d1.x;
    o.y = a.y + b1.y + c1.y + d1.y;
    o.z = a.z + b1.z + c1.z + d1.z;
    o.w = a.w + b1.w + c1.w + d1.w;
    ((float4*)out)[e4] = o;
}

extern "C" void kernel_launch(void* const* d_in, const int* in_sizes, int n_in,
                              void* d_out, int out_size, void* d_ws, size_t ws_size,
                              hipStream_t stream) {
    const float* x     = (const float*)d_in[0];
    const float* M     = (const float*)d_in[1];
    const float* P     = (const float*)d_in[2];
    const float* Lk    = (const float*)d_in[3];
    const float* gamma = (const float*)d_in[4];
    const float* beta  = (const float*)d_in[5];
    float* out = (float*)d_out;

    float* wsf = (float*)d_ws;
    _Float16*  xn16 = (_Float16*)(wsf + XN_OFF);    // f16 (B,S,D), dead after kB
    _Float16*  NT   = (_Float16*)(wsf + NT_OFF);    // f16 (B,D,S), written by kB
    _Float16*  LT   = (_Float16*)(wsf + LT_OFF);    // f16 (T,S)
    float*     part = wsf + XN_OFF;                 // reuse xn region

    hipLaunchKernelGGL(kA,  dim3(256),        dim3(256), 0, stream, x, M, gamma, beta, xn16);
    hipLaunchKernelGGL(kB,  dim3(512),        dim3(256), 0, stream, xn16, P, NT);
    hipLaunchKernelGGL(kXf, dim3(64, 16, 1),  dim3(256), 0, stream, Lk, LT, S_INN, S_OUTT);
    hipLaunchKernelGGL(kC,  dim3(64, 4),      dim3(512), 0, stream, NT, LT, part);
    hipLaunchKernelGGL(kD,  dim3(1024),       dim3(256), 0, stream, part, out);
}